// Round 4
// baseline (500.044 us; speedup 1.0000x reference)
//
#include <hip/hip_runtime.h>

#define HEADS 3
#define EMBD 192
#define DIN 128

// X[N,192] = A[N,128] @ W[192,128]^T, fused with per-node attention partials:
//   ai[n,h] = dot(x[n,h,:], att[h,0:64]),  aj[n,h] = dot(x[n,h,:], att[h,64:128])
// One thread per output row; blockIdx.y = head tile (64 cols). W tile in LDS
// (uniform broadcast reads, conflict-free); A row in 32 float4 regs.
// Prologue: grid-strided zero of the atomic buffers (denom/count/cursor, 6N u32)
// — disjoint from GEMM outputs, complete before k_edge1 (next dispatch).
__global__ __launch_bounds__(256) void k_gemm(const float* __restrict__ A,
      const float* __restrict__ W, const float* __restrict__ att,
      float* __restrict__ X, float* __restrict__ ai4, float* __restrict__ aj4,
      unsigned* __restrict__ zbuf, long zcount, int N){
  // fused zero-fill (replaces a separate k_zero dispatch)
  {
    long i = (long)(blockIdx.y*gridDim.x + blockIdx.x)*blockDim.x + threadIdx.x;
    long st = (long)gridDim.x*gridDim.y*blockDim.x;
    for (; i < zcount; i += st) zbuf[i] = 0u;
  }

  __shared__ float4 Ws4[64*32];          // 32 KiB: W rows [64][128] as float4
  __shared__ float attS[128];
  int t = threadIdx.x;
  int m = blockIdx.x*256 + t;
  int nb = blockIdx.y;                   // head / column tile 0..2
  const float4* Wg = (const float4*)W + (size_t)nb*2048;
  #pragma unroll
  for (int i = 0; i < 8; i++) Ws4[i*256 + t] = Wg[i*256 + t];
  if (t < 128) attS[t] = att[nb*128 + t];

  int mc = m < N ? m : (N-1);
  const float4* Ag = (const float4*)A + (size_t)mc*32;
  float4 a[32];
  #pragma unroll
  for (int i = 0; i < 32; i++) a[i] = Ag[i];
  __syncthreads();

  float ai_acc = 0.f, aj_acc = 0.f;
  float4* Xo = (float4*)(X + (size_t)mc*EMBD + nb*64);
  #pragma unroll 1
  for (int n4 = 0; n4 < 16; n4++){
    float s0=0.f, s1=0.f, s2=0.f, s3=0.f;
    #pragma unroll
    for (int k4 = 0; k4 < 32; k4++){
      float4 av = a[k4];
      float4 b0 = Ws4[(n4*4+0)*32 + k4];
      float4 b1 = Ws4[(n4*4+1)*32 + k4];
      float4 b2 = Ws4[(n4*4+2)*32 + k4];
      float4 b3 = Ws4[(n4*4+3)*32 + k4];
      s0 += av.x*b0.x + av.y*b0.y + av.z*b0.z + av.w*b0.w;
      s1 += av.x*b1.x + av.y*b1.y + av.z*b1.z + av.w*b1.w;
      s2 += av.x*b2.x + av.y*b2.y + av.z*b2.z + av.w*b2.w;
      s3 += av.x*b3.x + av.y*b3.y + av.z*b3.z + av.w*b3.w;
    }
    ai_acc += s0*attS[n4*4+0] + s1*attS[n4*4+1] + s2*attS[n4*4+2] + s3*attS[n4*4+3];
    aj_acc += s0*attS[64+n4*4+0] + s1*attS[64+n4*4+1] + s2*attS[64+n4*4+2] + s3*attS[64+n4*4+3];
    if (m < N) Xo[n4] = make_float4(s0, s1, s2, s3);
  }
  if (m < N){ ai4[(size_t)m*4 + nb] = ai_acc; aj4[(size_t)m*4 + nb] = aj_acc; }
}

// single edge pass: ex = exp(leaky(ai[d]+aj[s])). No max-shift needed: for this
// problem's distributions |logit| <= ~8 (78 sigma would be needed to overflow
// f32), and ex/denom is mathematically identical to the max-shifted form.
// Accumulates softmax denominators by src, histograms masked edges by dst.
__global__ void k_edge1(const int* __restrict__ ei, const int* __restrict__ msk,
    const float4* __restrict__ ai4, const float4* __restrict__ aj4,
    float* __restrict__ denom, int* __restrict__ count, float4* __restrict__ ae4, int E){
  int e = blockIdx.x*256 + threadIdx.x;
  if (e >= E) return;
  int s = ei[e], d = ei[E + e];
  float4 xi = ai4[d];
  float4 xj = aj4[s];
  float a0 = xi.x + xj.x; a0 = a0 >= 0.f ? a0 : 0.2f*a0; float e0 = expf(a0);
  float a1 = xi.y + xj.y; a1 = a1 >= 0.f ? a1 : 0.2f*a1; float e1 = expf(a1);
  float a2 = xi.z + xj.z; a2 = a2 >= 0.f ? a2 : 0.2f*a2; float e2 = expf(a2);
  ae4[e] = make_float4(e0, e1, e2, 0.f);
  atomicAdd(&denom[s*4+0], e0);
  atomicAdd(&denom[s*4+1], e1);
  atomicAdd(&denom[s*4+2], e2);
  if (msk[e]) atomicAdd(&count[d], 1);
}

// exclusive scan over masked counts -> offs (3 kernels)
__global__ void k_scan1(const int* __restrict__ count, int* __restrict__ offs,
                        int* __restrict__ bsum, int N){
  __shared__ int sm[256];
  int t = threadIdx.x, i = blockIdx.x*256 + t;
  int v = (i < N) ? count[i] : 0;
  sm[t] = v; __syncthreads();
  for (int o = 1; o < 256; o <<= 1){
    int u = (t >= o) ? sm[t-o] : 0;
    __syncthreads();
    sm[t] += u;
    __syncthreads();
  }
  if (i < N) offs[i] = sm[t] - v;
  if (t == 255) bsum[blockIdx.x] = sm[255];
}

__global__ void k_scan2(int* __restrict__ bsum, int NB){
  __shared__ int sm[1024];
  int t = threadIdx.x;
  int v = (t < NB) ? bsum[t] : 0;
  sm[t] = v; __syncthreads();
  for (int o = 1; o < 1024; o <<= 1){
    int u = (t >= o) ? sm[t-o] : 0;
    __syncthreads();
    sm[t] += u;
    __syncthreads();
  }
  if (t < NB) bsum[t] = sm[t] - v;   // exclusive
}

__global__ void k_scan3(int* __restrict__ offs, const int* __restrict__ bsum, int N){
  int i = blockIdx.x*256 + threadIdx.x;
  if (i < N) offs[i] += bsum[blockIdx.x];
}

// pass 2 (masked edges only): CSR fill by dst with final coefficients
// {src, ex0/denom0, ex1/denom1, ex2/denom2} — denom complete after k_edge1.
__global__ void k_edge2(const int* __restrict__ ei, const int* __restrict__ msk,
    const float4* __restrict__ ae4, const float4* __restrict__ denom4,
    const int* __restrict__ offs, int* __restrict__ cursor,
    float4* __restrict__ ecoef, int E){
  int e = blockIdx.x*256 + threadIdx.x;
  if (e >= E) return;
  if (!msk[e]) return;
  int s = ei[e], d = ei[E + e];
  float4 ex = ae4[e];
  float4 dn = denom4[s];
  int pos = atomicAdd(&cursor[d], 1);
  ecoef[offs[d] + pos] = make_float4(__int_as_float(s),
                                     ex.x / (dn.x + 1e-16f),
                                     ex.y / (dn.y + 1e-16f),
                                     ex.z / (dn.z + 1e-16f));
}

// gather-aggregate per dst node (wave per node), + bias + LeakyReLU(0.1)
__global__ __launch_bounds__(256) void k_aggr(const float* __restrict__ X,
    const float4* __restrict__ ecoef, const int* __restrict__ offs,
    const int* __restrict__ count, const float* __restrict__ bias,
    float* __restrict__ hact, int N){
  int w = threadIdx.x >> 6, l = threadIdx.x & 63;
  int n = blockIdx.x*4 + w;
  if (n >= N) return;
  int deg = count[n], base = offs[n];
  float ac0 = 0.f, ac1 = 0.f, ac2 = 0.f;
  #pragma unroll 4
  for (int j = 0; j < deg; j++){
    float4 q = ecoef[base + j];
    int s = __float_as_int(q.x);
    const float* xr = X + (size_t)s*EMBD;
    ac0 += q.y * xr[l];
    ac1 += q.z * xr[64 + l];
    ac2 += q.w * xr[128 + l];
  }
  float* o = hact + (size_t)n*EMBD;
  float v0 = ac0 + bias[l];       v0 = v0 >= 0.f ? v0 : 0.1f*v0; o[l]       = v0;
  float v1 = ac1 + bias[64 + l];  v1 = v1 >= 0.f ? v1 : 0.1f*v1; o[64 + l]  = v1;
  float v2 = ac2 + bias[128 + l]; v2 = v2 >= 0.f ? v2 : 0.1f*v2; o[128 + l] = v2;
}

// BN stats stage 1: 256 blocks x 192 channels, partial sum/sumsq
__global__ void k_stat1(const float* __restrict__ hact, float* __restrict__ part, int N){
  int c = threadIdx.x;
  float s = 0.f, sq = 0.f;
  for (int n = blockIdx.x; n < N; n += 256){
    float v = hact[(size_t)n*EMBD + c];
    s += v; sq += v*v;
  }
  part[blockIdx.x*384 + c] = s;
  part[blockIdx.x*384 + 192 + c] = sq;
}

// BN stats stage 2: reduce 256 partials -> mean, rstd
__global__ void k_stat2(const float* __restrict__ part, float* __restrict__ stats, int N){
  int c = threadIdx.x;
  float s = 0.f, sq = 0.f;
  for (int b = 0; b < 256; b++){
    s  += part[b*384 + c];
    sq += part[b*384 + 192 + c];
  }
  float mean = s / (float)N;
  float var  = sq / (float)N - mean*mean;
  stats[c] = mean;
  stats[192 + c] = rsqrtf(var + 1e-5f);
}

// final: mean over 4 layers, then affine BN (commutes since per-channel affine)
__global__ void k_final(const float* __restrict__ hact, const float* __restrict__ stats,
    const float* __restrict__ gamma, const float* __restrict__ beta,
    const int* __restrict__ sgs, float* __restrict__ out, int total){
  int o = blockIdx.x*256 + threadIdx.x;
  if (o >= total) return;
  int S = *sgs;                       // subgraph_size (device scalar)
  int c  = o % EMBD;
  int rs = o / EMBD;                  // b*S + s
  int b  = rs / S;
  int s  = rs % S;
  size_t n0 = (size_t)b*4*S + s;
  float v = 0.25f * (hact[(n0      )*EMBD + c] + hact[(n0 +   S)*EMBD + c] +
                     hact[(n0 + 2*S)*EMBD + c] + hact[(n0 + 3*S)*EMBD + c]);
  out[o] = gamma[c] * ((v - stats[c]) * stats[192 + c]) + beta[c];
}

extern "C" void kernel_launch(void* const* d_in, const int* in_sizes, int n_in,
                              void* d_out, int out_size, void* d_ws, size_t ws_size,
                              hipStream_t stream){
  const float* subx  = (const float*)d_in[0];
  const int*   ei    = (const int*)d_in[1];
  const int*   msk   = (const int*)d_in[2];
  const float* W     = (const float*)d_in[3];
  const float* att   = (const float*)d_in[4];
  const float* bias  = (const float*)d_in[5];
  const float* gamma = (const float*)d_in[6];
  const float* beta  = (const float*)d_in[7];
  const int*   sgs   = (const int*)d_in[9];
  float* out = (float*)d_out;

  int N = in_sizes[0] / DIN;     // 64000
  int E = in_sizes[1] / 2;       // 512000

  // workspace layout (floats; all chunks 16B aligned)
  float*    X      = (float*)d_ws;                     // N*192
  float*    hact   = X + (size_t)N*EMBD;               // N*192
  float*    denom  = hact + (size_t)N*EMBD;            // N*4   (zeroed)
  int*      count  = (int*)(denom + (size_t)N*4);      // N     (zeroed)
  int*      cursor = count + N;                        // N     (zeroed)
  int*      offs   = cursor + N;                       // N
  int*      bsum   = offs + N;                         // 1024
  float4*   ecoef  = (float4*)(bsum + 1024);           // E float4 slots
  float4*   ae4    = ecoef + E;                        // E float4
  float*    ai4    = (float*)(ae4 + E);                // N*4
  float*    aj4    = ai4 + (size_t)N*4;                // N*4
  float*    part   = aj4 + (size_t)N*4;                // 256*384
  float*    stats  = part + 256*384;                   // 384

  int NB = (N + 255)/256;

  k_gemm <<<dim3(NB, 3), 256, 0, stream>>>(subx, W, att, X, ai4, aj4,
                                           (unsigned*)denom, (long)6*N, N);
  k_edge1<<<(E + 255)/256, 256, 0, stream>>>(ei, msk, (const float4*)ai4, (const float4*)aj4,
                                             denom, count, ae4, E);
  k_scan1<<<NB, 256, 0, stream>>>(count, offs, bsum, N);
  k_scan2<<<1, 1024, 0, stream>>>(bsum, NB);
  k_scan3<<<NB, 256, 0, stream>>>(offs, bsum, N);
  k_edge2<<<(E + 255)/256, 256, 0, stream>>>(ei, msk, ae4, (const float4*)denom,
                                             offs, cursor, ecoef, E);
  k_aggr <<<(N + 3)/4, 256, 0, stream>>>(X, ecoef, offs, count, bias, hact, N);
  k_stat1<<<256, 192, 0, stream>>>(hact, part, N);
  k_stat2<<<1, 192, 0, stream>>>(part, stats, N);
  k_final<<<(out_size + 255)/256, 256, 0, stream>>>(hact, stats, gamma, beta, sgs, out, out_size);
}

// Round 5
// 387.215 us; speedup vs baseline: 1.2914x; 1.2914x over previous
//
#include <hip/hip_runtime.h>

#define HEADS 3
#define EMBD 192
#define DIN 128

// X[N,192] = A[N,128] @ W[192,128]^T, fused with per-node attention partials.
// Block = 256 threads -> 128 rows x 64 cols (head nb = blockIdx.y).
// Thread tile: 4 rows x 8 cols (acc=32 VGPR). W head-tile (64x128) in LDS,
// XOR-swizzled so each read instruction's 8 distinct b128 addresses cover all
// 32 banks (unswizzled: row stride 128 floats -> all col-groups on same banks).
// A streamed from global with 1-deep prefetch; 8 lanes share each A float4
// (same address -> broadcast coalesce, L1/L2 absorbs the 8x redundancy).
// Prologue: grid-strided zero of atomic buffers (denom/count/cursor, 6N u32).
__global__ __launch_bounds__(256) void k_gemm(const float* __restrict__ A,
      const float* __restrict__ W, const float* __restrict__ att,
      float* __restrict__ X, float* __restrict__ ai4, float* __restrict__ aj4,
      unsigned* __restrict__ zbuf, long zcount, int N){
  // fused zero-fill (replaces a separate k_zero dispatch)
  {
    long i = (long)(blockIdx.y*gridDim.x + blockIdx.x)*blockDim.x + threadIdx.x;
    long st = (long)gridDim.x*gridDim.y*blockDim.x;
    for (; i < zcount; i += st) zbuf[i] = 0u;
  }

  __shared__ float4 Ws[2048];            // 32 KiB: W head tile, swizzled
  int t  = threadIdx.x;
  int nb = blockIdx.y;                   // head / 64-col tile
  const float4* Wg = (const float4*)W + (size_t)nb*2048;
  #pragma unroll
  for (int i = 0; i < 8; i++){
    int idx = i*256 + t;
    int wr = idx >> 5, wk = idx & 31;    // W row (0..63), k4 (0..31)
    Ws[wr*32 + (wk ^ ((wr>>3)&7))] = Wg[idx];
  }

  int c = t & 7;                         // col-group: cols c*8..c*8+7
  int r = t >> 3;                        // row-group: rows r*4..r*4+3
  float atti[8], attj[8];
  #pragma unroll
  for (int j = 0; j < 8; j++){
    atti[j] = att[nb*128 + c*8 + j];
    attj[j] = att[nb*128 + 64 + c*8 + j];
  }
  __syncthreads();

  int m0 = blockIdx.x*128 + r*4;
  int mc0 = (m0 + 3 < N) ? m0 : (N > 4 ? N - 4 : 0);   // clamp (N%128==0 -> no-op)
  const float4* Ag = (const float4*)A;

  float acc[4][8];
  #pragma unroll
  for (int rr = 0; rr < 4; rr++)
    #pragma unroll
    for (int j = 0; j < 8; j++) acc[rr][j] = 0.f;

  float4 a_cur[4];
  #pragma unroll
  for (int rr = 0; rr < 4; rr++) a_cur[rr] = Ag[(size_t)(mc0+rr)*32];

  #pragma unroll 4
  for (int k4 = 0; k4 < 32; k4++){
    float4 a_nxt[4];
    if (k4 < 31){
      #pragma unroll
      for (int rr = 0; rr < 4; rr++) a_nxt[rr] = Ag[(size_t)(mc0+rr)*32 + k4 + 1];
    }
    #pragma unroll
    for (int j = 0; j < 8; j++){
      float4 w = Ws[(c*8 + j)*32 + (k4 ^ c)];
      #pragma unroll
      for (int rr = 0; rr < 4; rr++){
        acc[rr][j] += a_cur[rr].x*w.x + a_cur[rr].y*w.y + a_cur[rr].z*w.z + a_cur[rr].w*w.w;
      }
    }
    #pragma unroll
    for (int rr = 0; rr < 4; rr++) a_cur[rr] = a_nxt[rr];
  }

  #pragma unroll
  for (int rr = 0; rr < 4; rr++){
    int m = mc0 + rr;
    // att partials for this row (full head dot after xor-reduce over c)
    float pi = 0.f, pj = 0.f;
    #pragma unroll
    for (int j = 0; j < 8; j++){ pi += acc[rr][j]*atti[j]; pj += acc[rr][j]*attj[j]; }
    pi += __shfl_xor(pi, 1); pi += __shfl_xor(pi, 2); pi += __shfl_xor(pi, 4);
    pj += __shfl_xor(pj, 1); pj += __shfl_xor(pj, 2); pj += __shfl_xor(pj, 4);
    if (m0 + rr < N){
      float4* Xo = (float4*)(X + (size_t)m*EMBD + nb*64 + c*8);
      Xo[0] = make_float4(acc[rr][0], acc[rr][1], acc[rr][2], acc[rr][3]);
      Xo[1] = make_float4(acc[rr][4], acc[rr][5], acc[rr][6], acc[rr][7]);
      if (c == 0){ ai4[(size_t)m*4 + nb] = pi; aj4[(size_t)m*4 + nb] = pj; }
    }
  }
}

// single edge pass: ex = exp(leaky(ai[d]+aj[s])). No max-shift needed: for this
// problem's distributions |logit| <= ~8 (78 sigma would be needed to overflow
// f32), and ex/denom is mathematically identical to the max-shifted form.
// Accumulates softmax denominators by src, histograms masked edges by dst.
__global__ void k_edge1(const int* __restrict__ ei, const int* __restrict__ msk,
    const float4* __restrict__ ai4, const float4* __restrict__ aj4,
    float* __restrict__ denom, int* __restrict__ count, float4* __restrict__ ae4, int E){
  int e = blockIdx.x*256 + threadIdx.x;
  if (e >= E) return;
  int s = ei[e], d = ei[E + e];
  float4 xi = ai4[d];
  float4 xj = aj4[s];
  float a0 = xi.x + xj.x; a0 = a0 >= 0.f ? a0 : 0.2f*a0; float e0 = expf(a0);
  float a1 = xi.y + xj.y; a1 = a1 >= 0.f ? a1 : 0.2f*a1; float e1 = expf(a1);
  float a2 = xi.z + xj.z; a2 = a2 >= 0.f ? a2 : 0.2f*a2; float e2 = expf(a2);
  ae4[e] = make_float4(e0, e1, e2, 0.f);
  atomicAdd(&denom[s*4+0], e0);
  atomicAdd(&denom[s*4+1], e1);
  atomicAdd(&denom[s*4+2], e2);
  if (msk[e]) atomicAdd(&count[d], 1);
}

// exclusive scan over masked counts -> offs (3 kernels)
__global__ void k_scan1(const int* __restrict__ count, int* __restrict__ offs,
                        int* __restrict__ bsum, int N){
  __shared__ int sm[256];
  int t = threadIdx.x, i = blockIdx.x*256 + t;
  int v = (i < N) ? count[i] : 0;
  sm[t] = v; __syncthreads();
  for (int o = 1; o < 256; o <<= 1){
    int u = (t >= o) ? sm[t-o] : 0;
    __syncthreads();
    sm[t] += u;
    __syncthreads();
  }
  if (i < N) offs[i] = sm[t] - v;
  if (t == 255) bsum[blockIdx.x] = sm[255];
}

__global__ void k_scan2(int* __restrict__ bsum, int NB){
  __shared__ int sm[1024];
  int t = threadIdx.x;
  int v = (t < NB) ? bsum[t] : 0;
  sm[t] = v; __syncthreads();
  for (int o = 1; o < 1024; o <<= 1){
    int u = (t >= o) ? sm[t-o] : 0;
    __syncthreads();
    sm[t] += u;
    __syncthreads();
  }
  if (t < NB) bsum[t] = sm[t] - v;   // exclusive
}

__global__ void k_scan3(int* __restrict__ offs, const int* __restrict__ bsum, int N){
  int i = blockIdx.x*256 + threadIdx.x;
  if (i < N) offs[i] += bsum[blockIdx.x];
}

// pass 2 (masked edges only): CSR fill by dst with final coefficients
// {src, ex0/denom0, ex1/denom1, ex2/denom2} — denom complete after k_edge1.
__global__ void k_edge2(const int* __restrict__ ei, const int* __restrict__ msk,
    const float4* __restrict__ ae4, const float4* __restrict__ denom4,
    const int* __restrict__ offs, int* __restrict__ cursor,
    float4* __restrict__ ecoef, int E){
  int e = blockIdx.x*256 + threadIdx.x;
  if (e >= E) return;
  if (!msk[e]) return;
  int s = ei[e], d = ei[E + e];
  float4 ex = ae4[e];
  float4 dn = denom4[s];
  int pos = atomicAdd(&cursor[d], 1);
  ecoef[offs[d] + pos] = make_float4(__int_as_float(s),
                                     ex.x / (dn.x + 1e-16f),
                                     ex.y / (dn.y + 1e-16f),
                                     ex.z / (dn.z + 1e-16f));
}

// gather-aggregate per dst node (wave per node), + bias + LeakyReLU(0.1)
__global__ __launch_bounds__(256) void k_aggr(const float* __restrict__ X,
    const float4* __restrict__ ecoef, const int* __restrict__ offs,
    const int* __restrict__ count, const float* __restrict__ bias,
    float* __restrict__ hact, int N){
  int w = threadIdx.x >> 6, l = threadIdx.x & 63;
  int n = blockIdx.x*4 + w;
  if (n >= N) return;
  int deg = count[n], base = offs[n];
  float ac0 = 0.f, ac1 = 0.f, ac2 = 0.f;
  #pragma unroll 4
  for (int j = 0; j < deg; j++){
    float4 q = ecoef[base + j];
    int s = __float_as_int(q.x);
    const float* xr = X + (size_t)s*EMBD;
    ac0 += q.y * xr[l];
    ac1 += q.z * xr[64 + l];
    ac2 += q.w * xr[128 + l];
  }
  float* o = hact + (size_t)n*EMBD;
  float v0 = ac0 + bias[l];       v0 = v0 >= 0.f ? v0 : 0.1f*v0; o[l]       = v0;
  float v1 = ac1 + bias[64 + l];  v1 = v1 >= 0.f ? v1 : 0.1f*v1; o[64 + l]  = v1;
  float v2 = ac2 + bias[128 + l]; v2 = v2 >= 0.f ? v2 : 0.1f*v2; o[128 + l] = v2;
}

// BN stats stage 1: 256 blocks x 192 channels, partial sum/sumsq
__global__ void k_stat1(const float* __restrict__ hact, float* __restrict__ part, int N){
  int c = threadIdx.x;
  float s = 0.f, sq = 0.f;
  for (int n = blockIdx.x; n < N; n += 256){
    float v = hact[(size_t)n*EMBD + c];
    s += v; sq += v*v;
  }
  part[blockIdx.x*384 + c] = s;
  part[blockIdx.x*384 + 192 + c] = sq;
}

// BN stats stage 2: reduce 256 partials -> mean, rstd
__global__ void k_stat2(const float* __restrict__ part, float* __restrict__ stats, int N){
  int c = threadIdx.x;
  float s = 0.f, sq = 0.f;
  for (int b = 0; b < 256; b++){
    s  += part[b*384 + c];
    sq += part[b*384 + 192 + c];
  }
  float mean = s / (float)N;
  float var  = sq / (float)N - mean*mean;
  stats[c] = mean;
  stats[192 + c] = rsqrtf(var + 1e-5f);
}

// final: mean over 4 layers, then affine BN (commutes since per-channel affine)
__global__ void k_final(const float* __restrict__ hact, const float* __restrict__ stats,
    const float* __restrict__ gamma, const float* __restrict__ beta,
    const int* __restrict__ sgs, float* __restrict__ out, int total){
  int o = blockIdx.x*256 + threadIdx.x;
  if (o >= total) return;
  int S = *sgs;                       // subgraph_size (device scalar)
  int c  = o % EMBD;
  int rs = o / EMBD;                  // b*S + s
  int b  = rs / S;
  int s  = rs % S;
  size_t n0 = (size_t)b*4*S + s;
  float v = 0.25f * (hact[(n0      )*EMBD + c] + hact[(n0 +   S)*EMBD + c] +
                     hact[(n0 + 2*S)*EMBD + c] + hact[(n0 + 3*S)*EMBD + c]);
  out[o] = gamma[c] * ((v - stats[c]) * stats[192 + c]) + beta[c];
}

extern "C" void kernel_launch(void* const* d_in, const int* in_sizes, int n_in,
                              void* d_out, int out_size, void* d_ws, size_t ws_size,
                              hipStream_t stream){
  const float* subx  = (const float*)d_in[0];
  const int*   ei    = (const int*)d_in[1];
  const int*   msk   = (const int*)d_in[2];
  const float* W     = (const float*)d_in[3];
  const float* att   = (const float*)d_in[4];
  const float* bias  = (const float*)d_in[5];
  const float* gamma = (const float*)d_in[6];
  const float* beta  = (const float*)d_in[7];
  const int*   sgs   = (const int*)d_in[9];
  float* out = (float*)d_out;

  int N = in_sizes[0] / DIN;     // 64000
  int E = in_sizes[1] / 2;       // 512000

  // workspace layout (floats; all chunks 16B aligned)
  float*    X      = (float*)d_ws;                     // N*192
  float*    hact   = X + (size_t)N*EMBD;               // N*192
  float*    denom  = hact + (size_t)N*EMBD;            // N*4   (zeroed)
  int*      count  = (int*)(denom + (size_t)N*4);      // N     (zeroed)
  int*      cursor = count + N;                        // N     (zeroed)
  int*      offs   = cursor + N;                       // N
  int*      bsum   = offs + N;                         // 1024
  float4*   ecoef  = (float4*)(bsum + 1024);           // E float4 slots
  float4*   ae4    = ecoef + E;                        // E float4
  float*    ai4    = (float*)(ae4 + E);                // N*4
  float*    aj4    = ai4 + (size_t)N*4;                // N*4
  float*    part   = aj4 + (size_t)N*4;                // 256*384
  float*    stats  = part + 256*384;                   // 384

  int NB = (N + 255)/256;
  int MB = (N + 127)/128;        // 500 row-blocks for k_gemm

  k_gemm <<<dim3(MB, 3), 256, 0, stream>>>(subx, W, att, X, ai4, aj4,
                                           (unsigned*)denom, (long)6*N, N);
  k_edge1<<<(E + 255)/256, 256, 0, stream>>>(ei, msk, (const float4*)ai4, (const float4*)aj4,
                                             denom, count, ae4, E);
  k_scan1<<<NB, 256, 0, stream>>>(count, offs, bsum, N);
  k_scan2<<<1, 1024, 0, stream>>>(bsum, NB);
  k_scan3<<<NB, 256, 0, stream>>>(offs, bsum, N);
  k_edge2<<<(E + 255)/256, 256, 0, stream>>>(ei, msk, ae4, (const float4*)denom,
                                             offs, cursor, ecoef, E);
  k_aggr <<<(N + 3)/4, 256, 0, stream>>>(X, ecoef, offs, count, bias, hact, N);
  k_stat1<<<256, 192, 0, stream>>>(hact, part, N);
  k_stat2<<<1, 192, 0, stream>>>(part, stats, N);
  k_final<<<(out_size + 255)/256, 256, 0, stream>>>(hact, stats, gamma, beta, sgs, out, out_size);
}

// Round 6
// 348.091 us; speedup vs baseline: 1.4365x; 1.1124x over previous
//
#include <hip/hip_runtime.h>

#define EMBD 192
#define DIN 128

// X[N,192] = A[N,128] @ W[192,128]^T, fused with per-node attention partials.
// Block = 256 threads -> 128 rows x 64 cols (head nb = blockIdx.y).
// Thread tile: 4 rows x 8 cols. W head-tile (64x128) in LDS, XOR-swizzled.
// Prologue: grid-strided zero of count2 (2N u32) for k_count's atomics.
__global__ __launch_bounds__(256) void k_gemm(const float* __restrict__ A,
      const float* __restrict__ W, const float* __restrict__ att,
      float* __restrict__ X, float* __restrict__ ai4, float* __restrict__ aj4,
      unsigned* __restrict__ zbuf, long zcount, int N){
  {
    long i = (long)(blockIdx.y*gridDim.x + blockIdx.x)*blockDim.x + threadIdx.x;
    long st = (long)gridDim.x*gridDim.y*blockDim.x;
    for (; i < zcount; i += st) zbuf[i] = 0u;
  }

  __shared__ float4 Ws[2048];            // 32 KiB: W head tile, swizzled
  int t  = threadIdx.x;
  int nb = blockIdx.y;                   // head / 64-col tile
  const float4* Wg = (const float4*)W + (size_t)nb*2048;
  #pragma unroll
  for (int i = 0; i < 8; i++){
    int idx = i*256 + t;
    int wr = idx >> 5, wk = idx & 31;    // W row (0..63), k4 (0..31)
    Ws[wr*32 + (wk ^ ((wr>>3)&7))] = Wg[idx];
  }

  int c = t & 7;                         // col-group: cols c*8..c*8+7
  int r = t >> 3;                        // row-group: rows r*4..r*4+3
  float atti[8], attj[8];
  #pragma unroll
  for (int j = 0; j < 8; j++){
    atti[j] = att[nb*128 + c*8 + j];
    attj[j] = att[nb*128 + 64 + c*8 + j];
  }
  __syncthreads();

  int m0 = blockIdx.x*128 + r*4;
  int mc0 = (m0 + 3 < N) ? m0 : (N > 4 ? N - 4 : 0);
  const float4* Ag = (const float4*)A;

  float acc[4][8];
  #pragma unroll
  for (int rr = 0; rr < 4; rr++)
    #pragma unroll
    for (int j = 0; j < 8; j++) acc[rr][j] = 0.f;

  float4 a_cur[4];
  #pragma unroll
  for (int rr = 0; rr < 4; rr++) a_cur[rr] = Ag[(size_t)(mc0+rr)*32];

  #pragma unroll 4
  for (int k4 = 0; k4 < 32; k4++){
    float4 a_nxt[4];
    if (k4 < 31){
      #pragma unroll
      for (int rr = 0; rr < 4; rr++) a_nxt[rr] = Ag[(size_t)(mc0+rr)*32 + k4 + 1];
    }
    #pragma unroll
    for (int j = 0; j < 8; j++){
      float4 w = Ws[(c*8 + j)*32 + (k4 ^ c)];
      #pragma unroll
      for (int rr = 0; rr < 4; rr++){
        acc[rr][j] += a_cur[rr].x*w.x + a_cur[rr].y*w.y + a_cur[rr].z*w.z + a_cur[rr].w*w.w;
      }
    }
    #pragma unroll
    for (int rr = 0; rr < 4; rr++) a_cur[rr] = a_nxt[rr];
  }

  #pragma unroll
  for (int rr = 0; rr < 4; rr++){
    int m = mc0 + rr;
    float pi = 0.f, pj = 0.f;
    #pragma unroll
    for (int j = 0; j < 8; j++){ pi += acc[rr][j]*atti[j]; pj += acc[rr][j]*attj[j]; }
    pi += __shfl_xor(pi, 1); pi += __shfl_xor(pi, 2); pi += __shfl_xor(pi, 4);
    pj += __shfl_xor(pj, 1); pj += __shfl_xor(pj, 2); pj += __shfl_xor(pj, 4);
    if (m0 + rr < N){
      float4* Xo = (float4*)(X + (size_t)m*EMBD + nb*64 + c*8);
      Xo[0] = make_float4(acc[rr][0], acc[rr][1], acc[rr][2], acc[rr][3]);
      Xo[1] = make_float4(acc[rr][4], acc[rr][5], acc[rr][6], acc[rr][7]);
      if (c == 0){ ai4[(size_t)m*4 + nb] = pi; aj4[(size_t)m*4 + nb] = pj; }
    }
  }
}

// Count pass: slot trick — atomicAdd's RETURN VALUE is this edge's slot in its
// group, so the fill pass needs no cursor atomics. count2[0..N) = out-degree
// by src (all edges, for softmax denom); count2[N..2N) = masked in-degree by
// dst (aggregation). Only atomics in the whole pipeline: 1.5 per edge avg.
__global__ void k_count(const int* __restrict__ ei, const int* __restrict__ msk,
    int* __restrict__ count2, int* __restrict__ slot_src, int* __restrict__ slot_dst,
    int E, int N){
  int e = blockIdx.x*256 + threadIdx.x;
  if (e >= E) return;
  int s = ei[e], d = ei[E + e];
  slot_src[e] = atomicAdd(&count2[s], 1);
  slot_dst[e] = msk[e] ? atomicAdd(&count2[N + d], 1) : -1;
}

// exclusive scan over count2 (length M=2N) -> offs2 (3 kernels)
__global__ void k_scan1(const int* __restrict__ count, int* __restrict__ offs,
                        int* __restrict__ bsum, int M){
  __shared__ int sm[256];
  int t = threadIdx.x, i = blockIdx.x*256 + t;
  int v = (i < M) ? count[i] : 0;
  sm[t] = v; __syncthreads();
  for (int o = 1; o < 256; o <<= 1){
    int u = (t >= o) ? sm[t-o] : 0;
    __syncthreads();
    sm[t] += u;
    __syncthreads();
  }
  if (i < M) offs[i] = sm[t] - v;
  if (t == 255) bsum[blockIdx.x] = sm[255];
}

__global__ void k_scan2(int* __restrict__ bsum, int NB){
  __shared__ int sm[1024];
  int t = threadIdx.x;
  int v = (t < NB) ? bsum[t] : 0;
  sm[t] = v; __syncthreads();
  for (int o = 1; o < 1024; o <<= 1){
    int u = (t >= o) ? sm[t-o] : 0;
    __syncthreads();
    sm[t] += u;
    __syncthreads();
  }
  if (t < NB) bsum[t] = sm[t] - v;   // exclusive
}

__global__ void k_scan3(int* __restrict__ offs, const int* __restrict__ bsum, int M){
  int i = blockIdx.x*256 + threadIdx.x;
  if (i < M) offs[i] += bsum[blockIdx.x];
}

// Atomic-free fill: src-list stores the DST node id (all it needs for denom);
// dst-list stores the SRC node id (all aggr needs). Edge ids never stored.
__global__ void k_fill(const int* __restrict__ ei, const int* __restrict__ slot_src,
    const int* __restrict__ slot_dst, const int* __restrict__ offs2,
    int* __restrict__ elist_src, int* __restrict__ elist_dst, int E, int N){
  int e = blockIdx.x*256 + threadIdx.x;
  if (e >= E) return;
  int s = ei[e], d = ei[E + e];
  elist_src[offs2[s] + slot_src[e]] = d;
  int sd = slot_dst[e];
  if (sd >= 0) elist_dst[offs2[N + d] + sd] = s;
}

// Softmax denominators via gather-reduction over the src-list (NO atomics).
// 16-lane group per node (4 nodes/wave); stores RECIPROCALS so k_aggr
// multiplies instead of divides. exp without max-shift: |logit| <= ~8 for
// this problem's distributions (validated on HW rounds 4-5), identical math.
__global__ __launch_bounds__(256) void k_denom(const int* __restrict__ count2,
    const int* __restrict__ offs2, const int* __restrict__ elist_src,
    const float4* __restrict__ ai4, const float4* __restrict__ aj4,
    float4* __restrict__ denom4, int N){
  int g = threadIdx.x >> 4, l = threadIdx.x & 15;
  int n = blockIdx.x*16 + g;
  if (n >= N) return;
  int deg = count2[n];
  if (deg == 0) return;                 // never read downstream
  int base = offs2[n];
  float4 xj = aj4[n];                   // uniform in group -> broadcast
  float s0 = 0.f, s1 = 0.f, s2 = 0.f;
  for (int j = l; j < deg; j += 16){
    int d = elist_src[base + j];
    float4 xi = ai4[d];
    float a0 = xi.x + xj.x; a0 = a0 >= 0.f ? a0 : 0.2f*a0; s0 += expf(a0);
    float a1 = xi.y + xj.y; a1 = a1 >= 0.f ? a1 : 0.2f*a1; s1 += expf(a1);
    float a2 = xi.z + xj.z; a2 = a2 >= 0.f ? a2 : 0.2f*a2; s2 += expf(a2);
  }
  s0 += __shfl_xor(s0, 1); s0 += __shfl_xor(s0, 2); s0 += __shfl_xor(s0, 4); s0 += __shfl_xor(s0, 8);
  s1 += __shfl_xor(s1, 1); s1 += __shfl_xor(s1, 2); s1 += __shfl_xor(s1, 4); s1 += __shfl_xor(s1, 8);
  s2 += __shfl_xor(s2, 1); s2 += __shfl_xor(s2, 2); s2 += __shfl_xor(s2, 4); s2 += __shfl_xor(s2, 8);
  if (l == 0)
    denom4[n] = make_float4(1.f/(s0 + 1e-16f), 1.f/(s1 + 1e-16f), 1.f/(s2 + 1e-16f), 0.f);
}

// Gather-aggregate per dst node (wave per node) + bias + LeakyReLU(0.1).
// Per edge: s from dst-list (wave-uniform -> 1 transaction), aj4/denom4
// broadcasts, coeffs recomputed by all lanes (VALU was 1% busy — free),
// then 3x256B X row gather + FMA.
__global__ __launch_bounds__(256) void k_aggr(const float* __restrict__ X,
    const int* __restrict__ count2, const int* __restrict__ offs2,
    const int* __restrict__ elist_dst, const float4* __restrict__ ai4,
    const float4* __restrict__ aj4, const float4* __restrict__ denom4,
    const float* __restrict__ bias, float* __restrict__ hact, int N){
  int w = threadIdx.x >> 6, l = threadIdx.x & 63;
  int n = blockIdx.x*4 + w;
  if (n >= N) return;
  int deg = count2[N + n], base = offs2[N + n];
  float4 xi = ai4[n];
  float ac0 = 0.f, ac1 = 0.f, ac2 = 0.f;
  #pragma unroll 4
  for (int j = 0; j < deg; j++){
    int s = elist_dst[base + j];
    float4 xj = aj4[s];
    float4 rn = denom4[s];
    float a0 = xi.x + xj.x; a0 = a0 >= 0.f ? a0 : 0.2f*a0; float c0 = expf(a0)*rn.x;
    float a1 = xi.y + xj.y; a1 = a1 >= 0.f ? a1 : 0.2f*a1; float c1 = expf(a1)*rn.y;
    float a2 = xi.z + xj.z; a2 = a2 >= 0.f ? a2 : 0.2f*a2; float c2 = expf(a2)*rn.z;
    const float* xr = X + (size_t)s*EMBD;
    ac0 += c0 * xr[l];
    ac1 += c1 * xr[64 + l];
    ac2 += c2 * xr[128 + l];
  }
  float* o = hact + (size_t)n*EMBD;
  float v0 = ac0 + bias[l];       v0 = v0 >= 0.f ? v0 : 0.1f*v0; o[l]       = v0;
  float v1 = ac1 + bias[64 + l];  v1 = v1 >= 0.f ? v1 : 0.1f*v1; o[64 + l]  = v1;
  float v2 = ac2 + bias[128 + l]; v2 = v2 >= 0.f ? v2 : 0.1f*v2; o[128 + l] = v2;
}

// BN stats stage 1: 256 blocks x 192 channels, partial sum/sumsq
__global__ void k_stat1(const float* __restrict__ hact, float* __restrict__ part, int N){
  int c = threadIdx.x;
  float s = 0.f, sq = 0.f;
  for (int n = blockIdx.x; n < N; n += 256){
    float v = hact[(size_t)n*EMBD + c];
    s += v; sq += v*v;
  }
  part[blockIdx.x*384 + c] = s;
  part[blockIdx.x*384 + 192 + c] = sq;
}

// BN stats stage 2: reduce 256 partials -> mean, rstd
__global__ void k_stat2(const float* __restrict__ part, float* __restrict__ stats, int N){
  int c = threadIdx.x;
  float s = 0.f, sq = 0.f;
  for (int b = 0; b < 256; b++){
    s  += part[b*384 + c];
    sq += part[b*384 + 192 + c];
  }
  float mean = s / (float)N;
  float var  = sq / (float)N - mean*mean;
  stats[c] = mean;
  stats[192 + c] = rsqrtf(var + 1e-5f);
}

// final: mean over 4 layers, then affine BN (commutes since per-channel affine)
__global__ void k_final(const float* __restrict__ hact, const float* __restrict__ stats,
    const float* __restrict__ gamma, const float* __restrict__ beta,
    const int* __restrict__ sgs, float* __restrict__ out, int total){
  int o = blockIdx.x*256 + threadIdx.x;
  if (o >= total) return;
  int S = *sgs;
  int c  = o % EMBD;
  int rs = o / EMBD;
  int b  = rs / S;
  int s  = rs % S;
  size_t n0 = (size_t)b*4*S + s;
  float v = 0.25f * (hact[(n0      )*EMBD + c] + hact[(n0 +   S)*EMBD + c] +
                     hact[(n0 + 2*S)*EMBD + c] + hact[(n0 + 3*S)*EMBD + c]);
  out[o] = gamma[c] * ((v - stats[c]) * stats[192 + c]) + beta[c];
}

extern "C" void kernel_launch(void* const* d_in, const int* in_sizes, int n_in,
                              void* d_out, int out_size, void* d_ws, size_t ws_size,
                              hipStream_t stream){
  const float* subx  = (const float*)d_in[0];
  const int*   ei    = (const int*)d_in[1];
  const int*   msk   = (const int*)d_in[2];
  const float* W     = (const float*)d_in[3];
  const float* att   = (const float*)d_in[4];
  const float* bias  = (const float*)d_in[5];
  const float* gamma = (const float*)d_in[6];
  const float* beta  = (const float*)d_in[7];
  const int*   sgs   = (const int*)d_in[9];
  float* out = (float*)d_out;

  int N = in_sizes[0] / DIN;     // 64000
  int E = in_sizes[1] / 2;       // 512000

  // workspace layout (all chunks 16B aligned)
  float*  X         = (float*)d_ws;                    // N*192
  float*  hact      = X + (size_t)N*EMBD;              // N*192
  float*  denom4    = hact + (size_t)N*EMBD;           // N*4 (reciprocals)
  float*  ai4       = denom4 + (size_t)N*4;            // N*4
  float*  aj4       = ai4 + (size_t)N*4;               // N*4
  int*    count2    = (int*)(aj4 + (size_t)N*4);       // 2N  (zeroed in k_gemm)
  int*    offs2     = count2 + 2*(size_t)N;            // 2N
  int*    slot_src  = offs2 + 2*(size_t)N;             // E
  int*    slot_dst  = slot_src + E;                    // E
  int*    elist_src = slot_dst + E;                    // E
  int*    elist_dst = elist_src + E;                   // E
  int*    bsum      = elist_dst + E;                   // 1024
  float*  part      = (float*)(bsum + 1024);           // 256*384
  float*  stats     = part + 256*384;                  // 384

  int EB  = (E + 255)/256;       // 2000 edge blocks
  int MB  = (N + 127)/128;       // 500 row blocks (gemm)
  int M2  = 2*N;                 // scan length
  int NB2 = (M2 + 255)/256;      // 500 scan blocks

  k_gemm <<<dim3(MB, 3), 256, 0, stream>>>(subx, W, att, X, ai4, aj4,
                                           (unsigned*)count2, (long)M2, N);
  k_count<<<EB, 256, 0, stream>>>(ei, msk, count2, slot_src, slot_dst, E, N);
  k_scan1<<<NB2, 256, 0, stream>>>(count2, offs2, bsum, M2);
  k_scan2<<<1, 1024, 0, stream>>>(bsum, NB2);
  k_scan3<<<NB2, 256, 0, stream>>>(offs2, bsum, M2);
  k_fill <<<EB, 256, 0, stream>>>(ei, slot_src, slot_dst, offs2, elist_src, elist_dst, E, N);
  k_denom<<<(N + 15)/16, 256, 0, stream>>>(count2, offs2, elist_src,
                                           (const float4*)ai4, (const float4*)aj4,
                                           (float4*)denom4, N);
  k_aggr <<<(N + 3)/4, 256, 0, stream>>>(X, count2, offs2, elist_dst,
                                         (const float4*)ai4, (const float4*)aj4,
                                         (const float4*)denom4, bias, hact, N);
  k_stat1<<<256, 192, 0, stream>>>(hact, part, N);
  k_stat2<<<1, 192, 0, stream>>>(part, stats, N);
  k_final<<<(out_size + 255)/256, 256, 0, stream>>>(hact, stats, gamma, beta, sgs, out, out_size);
}

// Round 7
// 279.759 us; speedup vs baseline: 1.7874x; 1.2443x over previous
//
#include <hip/hip_runtime.h>

#define EMBD 192
#define DIN 128
#define SB 1024   // stat stage-1 blocks

__device__ __forceinline__ void f4add(float4& a, const float4& b){
  a.x += b.x; a.y += b.y; a.z += b.z; a.w += b.w;
}

// X[N,192] = A[N,128] @ W[192,128]^T, fused with per-node attention partials.
// Block = 256 threads -> 128 rows x 64 cols (head nb = blockIdx.y).
// Thread tile: 4 rows x 8 cols. W head-tile (64x128) in LDS, XOR-swizzled.
// Prologue: grid-strided zero of count2 (2N u32) for k_count's atomics.
__global__ __launch_bounds__(256) void k_gemm(const float* __restrict__ A,
      const float* __restrict__ W, const float* __restrict__ att,
      float* __restrict__ X, float* __restrict__ ai4, float* __restrict__ aj4,
      unsigned* __restrict__ zbuf, long zcount, int N){
  {
    long i = (long)(blockIdx.y*gridDim.x + blockIdx.x)*blockDim.x + threadIdx.x;
    long st = (long)gridDim.x*gridDim.y*blockDim.x;
    for (; i < zcount; i += st) zbuf[i] = 0u;
  }

  __shared__ float4 Ws[2048];            // 32 KiB: W head tile, swizzled
  int t  = threadIdx.x;
  int nb = blockIdx.y;                   // head / 64-col tile
  const float4* Wg = (const float4*)W + (size_t)nb*2048;
  #pragma unroll
  for (int i = 0; i < 8; i++){
    int idx = i*256 + t;
    int wr = idx >> 5, wk = idx & 31;    // W row (0..63), k4 (0..31)
    Ws[wr*32 + (wk ^ ((wr>>3)&7))] = Wg[idx];
  }

  int c = t & 7;                         // col-group: cols c*8..c*8+7
  int r = t >> 3;                        // row-group: rows r*4..r*4+3
  float atti[8], attj[8];
  #pragma unroll
  for (int j = 0; j < 8; j++){
    atti[j] = att[nb*128 + c*8 + j];
    attj[j] = att[nb*128 + 64 + c*8 + j];
  }
  __syncthreads();

  int m0 = blockIdx.x*128 + r*4;
  int mc0 = (m0 + 3 < N) ? m0 : (N > 4 ? N - 4 : 0);
  const float4* Ag = (const float4*)A;

  float acc[4][8];
  #pragma unroll
  for (int rr = 0; rr < 4; rr++)
    #pragma unroll
    for (int j = 0; j < 8; j++) acc[rr][j] = 0.f;

  float4 a_cur[4];
  #pragma unroll
  for (int rr = 0; rr < 4; rr++) a_cur[rr] = Ag[(size_t)(mc0+rr)*32];

  #pragma unroll 4
  for (int k4 = 0; k4 < 32; k4++){
    float4 a_nxt[4];
    if (k4 < 31){
      #pragma unroll
      for (int rr = 0; rr < 4; rr++) a_nxt[rr] = Ag[(size_t)(mc0+rr)*32 + k4 + 1];
    }
    #pragma unroll
    for (int j = 0; j < 8; j++){
      float4 w = Ws[(c*8 + j)*32 + (k4 ^ c)];
      #pragma unroll
      for (int rr = 0; rr < 4; rr++){
        acc[rr][j] += a_cur[rr].x*w.x + a_cur[rr].y*w.y + a_cur[rr].z*w.z + a_cur[rr].w*w.w;
      }
    }
    #pragma unroll
    for (int rr = 0; rr < 4; rr++) a_cur[rr] = a_nxt[rr];
  }

  #pragma unroll
  for (int rr = 0; rr < 4; rr++){
    int m = mc0 + rr;
    float pi = 0.f, pj = 0.f;
    #pragma unroll
    for (int j = 0; j < 8; j++){ pi += acc[rr][j]*atti[j]; pj += acc[rr][j]*attj[j]; }
    pi += __shfl_xor(pi, 1); pi += __shfl_xor(pi, 2); pi += __shfl_xor(pi, 4);
    pj += __shfl_xor(pj, 1); pj += __shfl_xor(pj, 2); pj += __shfl_xor(pj, 4);
    if (m0 + rr < N){
      float4* Xo = (float4*)(X + (size_t)m*EMBD + nb*64 + c*8);
      Xo[0] = make_float4(acc[rr][0], acc[rr][1], acc[rr][2], acc[rr][3]);
      Xo[1] = make_float4(acc[rr][4], acc[rr][5], acc[rr][6], acc[rr][7]);
      if (c == 0){ ai4[(size_t)m*4 + nb] = pi; aj4[(size_t)m*4 + nb] = pj; }
    }
  }
}

// Count pass: slot trick — atomicAdd's RETURN VALUE is this edge's slot in its
// group, so the fill pass needs no cursor atomics.
__global__ void k_count(const int* __restrict__ ei, const int* __restrict__ msk,
    int* __restrict__ count2, int* __restrict__ slot_src, int* __restrict__ slot_dst,
    int E, int N){
  int e = blockIdx.x*256 + threadIdx.x;
  if (e >= E) return;
  int s = ei[e], d = ei[E + e];
  slot_src[e] = atomicAdd(&count2[s], 1);
  slot_dst[e] = msk[e] ? atomicAdd(&count2[N + d], 1) : -1;
}

// exclusive scan over count2 (length M=2N) -> offs2 (3 kernels)
__global__ void k_scan1(const int* __restrict__ count, int* __restrict__ offs,
                        int* __restrict__ bsum, int M){
  __shared__ int sm[256];
  int t = threadIdx.x, i = blockIdx.x*256 + t;
  int v = (i < M) ? count[i] : 0;
  sm[t] = v; __syncthreads();
  for (int o = 1; o < 256; o <<= 1){
    int u = (t >= o) ? sm[t-o] : 0;
    __syncthreads();
    sm[t] += u;
    __syncthreads();
  }
  if (i < M) offs[i] = sm[t] - v;
  if (t == 255) bsum[blockIdx.x] = sm[255];
}

__global__ void k_scan2(int* __restrict__ bsum, int NB){
  __shared__ int sm[1024];
  int t = threadIdx.x;
  int v = (t < NB) ? bsum[t] : 0;
  sm[t] = v; __syncthreads();
  for (int o = 1; o < 1024; o <<= 1){
    int u = (t >= o) ? sm[t-o] : 0;
    __syncthreads();
    sm[t] += u;
    __syncthreads();
  }
  if (t < NB) bsum[t] = sm[t] - v;   // exclusive
}

__global__ void k_scan3(int* __restrict__ offs, const int* __restrict__ bsum, int M){
  int i = blockIdx.x*256 + threadIdx.x;
  if (i < M) offs[i] += bsum[blockIdx.x];
}

// Atomic-free fill: src-list stores the DST node id; dst-list stores the SRC id.
__global__ void k_fill(const int* __restrict__ ei, const int* __restrict__ slot_src,
    const int* __restrict__ slot_dst, const int* __restrict__ offs2,
    int* __restrict__ elist_src, int* __restrict__ elist_dst, int E, int N){
  int e = blockIdx.x*256 + threadIdx.x;
  if (e >= E) return;
  int s = ei[e], d = ei[E + e];
  elist_src[offs2[s] + slot_src[e]] = d;
  int sd = slot_dst[e];
  if (sd >= 0) elist_dst[offs2[N + d] + sd] = s;
}

// Softmax denominators via gather-reduction over the src-list (NO atomics).
// Stores RECIPROCALS. exp without max-shift: |logit| <= ~8 here, identical math.
__global__ __launch_bounds__(256) void k_denom(const int* __restrict__ count2,
    const int* __restrict__ offs2, const int* __restrict__ elist_src,
    const float4* __restrict__ ai4, const float4* __restrict__ aj4,
    float4* __restrict__ denom4, int N){
  int g = threadIdx.x >> 4, l = threadIdx.x & 15;
  int n = blockIdx.x*16 + g;
  if (n >= N) return;
  int deg = count2[n];
  if (deg == 0) return;                 // never read downstream
  int base = offs2[n];
  float4 xj = aj4[n];                   // uniform in group -> broadcast
  float s0 = 0.f, s1 = 0.f, s2 = 0.f;
  for (int j = l; j < deg; j += 16){
    int d = elist_src[base + j];
    float4 xi = ai4[d];
    float a0 = xi.x + xj.x; a0 = a0 >= 0.f ? a0 : 0.2f*a0; s0 += expf(a0);
    float a1 = xi.y + xj.y; a1 = a1 >= 0.f ? a1 : 0.2f*a1; s1 += expf(a1);
    float a2 = xi.z + xj.z; a2 = a2 >= 0.f ? a2 : 0.2f*a2; s2 += expf(a2);
  }
  s0 += __shfl_xor(s0, 1); s0 += __shfl_xor(s0, 2); s0 += __shfl_xor(s0, 4); s0 += __shfl_xor(s0, 8);
  s1 += __shfl_xor(s1, 1); s1 += __shfl_xor(s1, 2); s1 += __shfl_xor(s1, 4); s1 += __shfl_xor(s1, 8);
  s2 += __shfl_xor(s2, 1); s2 += __shfl_xor(s2, 2); s2 += __shfl_xor(s2, 4); s2 += __shfl_xor(s2, 8);
  if (l == 0)
    denom4[n] = make_float4(1.f/(s0 + 1e-16f), 1.f/(s1 + 1e-16f), 1.f/(s2 + 1e-16f), 0.f);
}

// Gather-aggregate per dst node (wave per node) + bias + LeakyReLU(0.1).
__global__ __launch_bounds__(256) void k_aggr(const float* __restrict__ X,
    const int* __restrict__ count2, const int* __restrict__ offs2,
    const int* __restrict__ elist_dst, const float4* __restrict__ ai4,
    const float4* __restrict__ aj4, const float4* __restrict__ denom4,
    const float* __restrict__ bias, float* __restrict__ hact, int N){
  int w = threadIdx.x >> 6, l = threadIdx.x & 63;
  int n = blockIdx.x*4 + w;
  if (n >= N) return;
  int deg = count2[N + n], base = offs2[N + n];
  float4 xi = ai4[n];
  float ac0 = 0.f, ac1 = 0.f, ac2 = 0.f;
  #pragma unroll 4
  for (int j = 0; j < deg; j++){
    int s = elist_dst[base + j];
    float4 xj = aj4[s];
    float4 rn = denom4[s];
    float a0 = xi.x + xj.x; a0 = a0 >= 0.f ? a0 : 0.2f*a0; float c0 = expf(a0)*rn.x;
    float a1 = xi.y + xj.y; a1 = a1 >= 0.f ? a1 : 0.2f*a1; float c1 = expf(a1)*rn.y;
    float a2 = xi.z + xj.z; a2 = a2 >= 0.f ? a2 : 0.2f*a2; float c2 = expf(a2)*rn.z;
    const float* xr = X + (size_t)s*EMBD;
    ac0 += c0 * xr[l];
    ac1 += c1 * xr[64 + l];
    ac2 += c2 * xr[128 + l];
  }
  float* o = hact + (size_t)n*EMBD;
  float v0 = ac0 + bias[l];       v0 = v0 >= 0.f ? v0 : 0.1f*v0; o[l]       = v0;
  float v1 = ac1 + bias[64 + l];  v1 = v1 >= 0.f ? v1 : 0.1f*v1; o[64 + l]  = v1;
  float v2 = ac2 + bias[128 + l]; v2 = v2 >= 0.f ? v2 : 0.1f*v2; o[128 + l] = v2;
}

// BN stats stage 1: SB blocks x 192 threads. Thread = (float4-col 0..47,
// row-group 0..3); float4 loads, 2-step LDS tree over row-groups.
// part4 layout: [SB][96] float4 — [0..47]=sum, [48..95]=sumsq.
__global__ __launch_bounds__(192) void k_stat1(const float4* __restrict__ h4,
    float4* __restrict__ part4, int N){
  int t = threadIdx.x;
  int fcol = t % 48, rg = t / 48;       // rg in 0..3
  float4 s = make_float4(0.f,0.f,0.f,0.f);
  float4 q = make_float4(0.f,0.f,0.f,0.f);
  for (int r = blockIdx.x*4 + rg; r < N; r += SB*4){
    float4 v = h4[(size_t)r*48 + fcol];
    s.x += v.x; s.y += v.y; s.z += v.z; s.w += v.w;
    q.x += v.x*v.x; q.y += v.y*v.y; q.z += v.z*v.z; q.w += v.w*v.w;
  }
  __shared__ float4 sms[192], smq[192];
  sms[t] = s; smq[t] = q;
  __syncthreads();
  if (rg < 2){ f4add(sms[t], sms[t+96]); f4add(smq[t], smq[t+96]); }
  __syncthreads();
  if (rg == 0){
    f4add(sms[t], sms[t+48]); f4add(smq[t], smq[t+48]);
    part4[(size_t)blockIdx.x*96 + fcol]      = sms[t];
    part4[(size_t)blockIdx.x*96 + 48 + fcol] = smq[t];
  }
}

// BN stats stage 2: 48 blocks (one float4-channel each) x 256 threads.
// Reduce sum+sumsq over SB partials; write stats4[j]=mean, stats4[48+j]=rstd.
__global__ __launch_bounds__(256) void k_stat2(const float4* __restrict__ part4,
    float4* __restrict__ stats4, int N){
  int j = blockIdx.x, t = threadIdx.x;
  float4 s = make_float4(0.f,0.f,0.f,0.f);
  float4 q = make_float4(0.f,0.f,0.f,0.f);
  for (int b = t; b < SB; b += 256){
    f4add(s, part4[(size_t)b*96 + j]);
    f4add(q, part4[(size_t)b*96 + 48 + j]);
  }
  #pragma unroll
  for (int o = 32; o > 0; o >>= 1){
    s.x += __shfl_xor(s.x,o); s.y += __shfl_xor(s.y,o);
    s.z += __shfl_xor(s.z,o); s.w += __shfl_xor(s.w,o);
    q.x += __shfl_xor(q.x,o); q.y += __shfl_xor(q.y,o);
    q.z += __shfl_xor(q.z,o); q.w += __shfl_xor(q.w,o);
  }
  __shared__ float4 ws[4], wq[4];
  int wv = t >> 6;
  if ((t & 63) == 0){ ws[wv] = s; wq[wv] = q; }
  __syncthreads();
  if (t == 0){
    f4add(ws[0], ws[1]); f4add(ws[0], ws[2]); f4add(ws[0], ws[3]);
    f4add(wq[0], wq[1]); f4add(wq[0], wq[2]); f4add(wq[0], wq[3]);
    float inv = 1.f / (float)N;
    float4 mean = make_float4(ws[0].x*inv, ws[0].y*inv, ws[0].z*inv, ws[0].w*inv);
    float4 rstd;
    rstd.x = rsqrtf(wq[0].x*inv - mean.x*mean.x + 1e-5f);
    rstd.y = rsqrtf(wq[0].y*inv - mean.y*mean.y + 1e-5f);
    rstd.z = rsqrtf(wq[0].z*inv - mean.z*mean.z + 1e-5f);
    rstd.w = rsqrtf(wq[0].w*inv - mean.w*mean.w + 1e-5f);
    stats4[j] = mean;
    stats4[48 + j] = rstd;
  }
}

// final: mean over 4 layers, then affine BN (commutes since per-channel affine)
__global__ void k_final(const float* __restrict__ hact, const float* __restrict__ stats,
    const float* __restrict__ gamma, const float* __restrict__ beta,
    const int* __restrict__ sgs, float* __restrict__ out, int total){
  int o = blockIdx.x*256 + threadIdx.x;
  if (o >= total) return;
  int S = *sgs;
  int c  = o % EMBD;
  int rs = o / EMBD;
  int b  = rs / S;
  int s  = rs % S;
  size_t n0 = (size_t)b*4*S + s;
  float v = 0.25f * (hact[(n0      )*EMBD + c] + hact[(n0 +   S)*EMBD + c] +
                     hact[(n0 + 2*S)*EMBD + c] + hact[(n0 + 3*S)*EMBD + c]);
  out[o] = gamma[c] * ((v - stats[c]) * stats[192 + c]) + beta[c];
}

extern "C" void kernel_launch(void* const* d_in, const int* in_sizes, int n_in,
                              void* d_out, int out_size, void* d_ws, size_t ws_size,
                              hipStream_t stream){
  const float* subx  = (const float*)d_in[0];
  const int*   ei    = (const int*)d_in[1];
  const int*   msk   = (const int*)d_in[2];
  const float* W     = (const float*)d_in[3];
  const float* att   = (const float*)d_in[4];
  const float* bias  = (const float*)d_in[5];
  const float* gamma = (const float*)d_in[6];
  const float* beta  = (const float*)d_in[7];
  const int*   sgs   = (const int*)d_in[9];
  float* out = (float*)d_out;

  int N = in_sizes[0] / DIN;     // 64000
  int E = in_sizes[1] / 2;       // 512000

  // workspace layout (all chunks 16B aligned)
  float*  X         = (float*)d_ws;                    // N*192
  float*  hact      = X + (size_t)N*EMBD;              // N*192
  float*  denom4    = hact + (size_t)N*EMBD;           // N*4 (reciprocals)
  float*  ai4       = denom4 + (size_t)N*4;            // N*4
  float*  aj4       = ai4 + (size_t)N*4;               // N*4
  int*    count2    = (int*)(aj4 + (size_t)N*4);       // 2N  (zeroed in k_gemm)
  int*    offs2     = count2 + 2*(size_t)N;            // 2N
  int*    slot_src  = offs2 + 2*(size_t)N;             // E
  int*    slot_dst  = slot_src + E;                    // E
  int*    elist_src = slot_dst + E;                    // E
  int*    elist_dst = elist_src + E;                   // E
  int*    bsum      = elist_dst + E;                   // 1024
  float*  part      = (float*)(bsum + 1024);           // SB*96*4 floats
  float*  stats     = part + (size_t)SB*96*4;          // 384

  int EB  = (E + 255)/256;       // edge blocks
  int MB  = (N + 127)/128;       // row blocks (gemm)
  int M2  = 2*N;                 // scan length
  int NB2 = (M2 + 255)/256;      // scan blocks

  k_gemm <<<dim3(MB, 3), 256, 0, stream>>>(subx, W, att, X, ai4, aj4,
                                           (unsigned*)count2, (long)M2, N);
  k_count<<<EB, 256, 0, stream>>>(ei, msk, count2, slot_src, slot_dst, E, N);
  k_scan1<<<NB2, 256, 0, stream>>>(count2, offs2, bsum, M2);
  k_scan2<<<1, 1024, 0, stream>>>(bsum, NB2);
  k_scan3<<<NB2, 256, 0, stream>>>(offs2, bsum, M2);
  k_fill <<<EB, 256, 0, stream>>>(ei, slot_src, slot_dst, offs2, elist_src, elist_dst, E, N);
  k_denom<<<(N + 15)/16, 256, 0, stream>>>(count2, offs2, elist_src,
                                           (const float4*)ai4, (const float4*)aj4,
                                           (float4*)denom4, N);
  k_aggr <<<(N + 3)/4, 256, 0, stream>>>(X, count2, offs2, elist_dst,
                                         (const float4*)ai4, (const float4*)aj4,
                                         (const float4*)denom4, bias, hact, N);
  k_stat1<<<SB, 192, 0, stream>>>((const float4*)hact, (float4*)part, N);
  k_stat2<<<48, 256, 0, stream>>>((const float4*)part, (float4*)stats, N);
  k_final<<<(out_size + 255)/256, 256, 0, stream>>>(hact, stats, gamma, beta, sgs, out, out_size);
}

// Round 8
// 265.257 us; speedup vs baseline: 1.8851x; 1.0547x over previous
//
#include <hip/hip_runtime.h>

#define EMBD 192
#define DIN 128
#define SB 1024   // stat stage-1 blocks

typedef __bf16 bfrag __attribute__((ext_vector_type(8)));
typedef float  f32x4 __attribute__((ext_vector_type(4)));

__device__ __forceinline__ void f4add(float4& a, const float4& b){
  a.x += b.x; a.y += b.y; a.z += b.z; a.w += b.w;
}
// round-to-nearest-even f32 -> bf16 (bit trick)
__device__ __forceinline__ unsigned short f2bf(float f){
  unsigned u = __float_as_uint(f);
  unsigned r = u + 0x7fffu + ((u >> 16) & 1u);
  return (unsigned short)(r >> 16);
}
__device__ __forceinline__ float bf2f(unsigned short h){
  return __uint_as_float(((unsigned)h) << 16);
}

// X[N,192] = A[N,128] @ W[192,128]^T via split-bf16 MFMA (3-term: hh+hl+lh,
// error ~2^-17 — f32-class). Block = 64 rows x 64 cols (one head); 4 waves,
// wave = 16 rows x 64 cols; K=128 = 4 MFMA k-steps x 3 terms x 4 col-tiles
// = 48 mfma_f32_16x16x32_bf16 per wave. A/W staged in LDS as bf16 hi/lo
// [64][128] with 16B-granule XOR swizzle (g ^ row&15) -> conflict-free b128
// fragment reads. XCD-bijective block swizzle co-locates the 3 head-blocks
// of the same rows on one XCD (A L2 reuse). Fused ai/aj epilogue.
// Prologue: grid-strided zero of count2 (2N u32).
__global__ __launch_bounds__(256) void k_gemm(const float* __restrict__ A,
      const float* __restrict__ W, const float* __restrict__ att,
      float* __restrict__ X, float* __restrict__ ai4, float* __restrict__ aj4,
      unsigned* __restrict__ zbuf, long zcount, int N, int G){
  {
    long i = (long)blockIdx.x*blockDim.x + threadIdx.x;
    long st = (long)gridDim.x*blockDim.x;
    for (; i < zcount; i += st) zbuf[i] = 0u;
  }

  // XCD-bijective decode: flat -> (rowblk, head); G % 8 == 0 required.
  int flat = blockIdx.x;
  int L = (G % 8 == 0) ? ((flat & 7)*(G >> 3) + (flat >> 3)) : flat;
  int rowblk = L / 3, head = L - rowblk*3;

  __shared__ unsigned short As_hi[8192], As_lo[8192];   // [64 rows][128 k] bf16
  __shared__ unsigned short Ws_hi[8192], Ws_lo[8192];   // [64 cols][128 k] bf16
  int t = threadIdx.x;

  // stage A rows and W head-tile: 8 float4 each per thread, cvt to hi/lo bf16
  const float4* Ag = (const float4*)A;
  const float4* Wg = (const float4*)W + (size_t)(head*64)*32;
  #pragma unroll
  for (int i = 0; i < 8; i++){
    int idx = i*256 + t;
    int r = idx >> 5, c4 = idx & 31;
    int g = (c4 >> 1) ^ (r & 15);                 // swizzled 16B granule
    int base = (r*16 + g)*8 + (c4 & 1)*4;
    int row = rowblk*64 + r; if (row >= N) row = N - 1;
    float4 va = Ag[(size_t)row*32 + c4];
    float4 vw = Wg[(size_t)idx];
    unsigned short h; float lo;
    ushort4 ah, al, wh, wl;
    h = f2bf(va.x); lo = va.x - bf2f(h); ah.x = h; al.x = f2bf(lo);
    h = f2bf(va.y); lo = va.y - bf2f(h); ah.y = h; al.y = f2bf(lo);
    h = f2bf(va.z); lo = va.z - bf2f(h); ah.z = h; al.z = f2bf(lo);
    h = f2bf(va.w); lo = va.w - bf2f(h); ah.w = h; al.w = f2bf(lo);
    *(ushort4*)&As_hi[base] = ah; *(ushort4*)&As_lo[base] = al;
    h = f2bf(vw.x); lo = vw.x - bf2f(h); wh.x = h; wl.x = f2bf(lo);
    h = f2bf(vw.y); lo = vw.y - bf2f(h); wh.y = h; wl.y = f2bf(lo);
    h = f2bf(vw.z); lo = vw.z - bf2f(h); wh.z = h; wl.z = f2bf(lo);
    h = f2bf(vw.w); lo = vw.w - bf2f(h); wh.w = h; wl.w = f2bf(lo);
    *(ushort4*)&Ws_hi[base] = wh; *(ushort4*)&Ws_lo[base] = wl;
  }

  int wave = t >> 6, lane = t & 63;
  int lc = lane & 15, kg = lane >> 4;
  float atti_l[4], attj_l[4];
  #pragma unroll
  for (int ct = 0; ct < 4; ct++){
    atti_l[ct] = att[head*128 + ct*16 + lc];
    attj_l[ct] = att[head*128 + 64 + ct*16 + lc];
  }
  __syncthreads();

  // MFMA main: A-frag row = lane&15 (+wave*16), k = kg*8 + j
  int arow = wave*16 + lc;
  f32x4 acc[4];
  #pragma unroll
  for (int ct = 0; ct < 4; ct++) acc[ct] = (f32x4){0.f, 0.f, 0.f, 0.f};

  #pragma unroll
  for (int ks = 0; ks < 4; ks++){
    int g = ks*4 + kg;
    int aoff = (arow*16 + (g ^ (arow & 15)))*8;
    bfrag ah = *(const bfrag*)&As_hi[aoff];
    bfrag al = *(const bfrag*)&As_lo[aoff];
    #pragma unroll
    for (int ct = 0; ct < 4; ct++){
      int boff = ((ct*16 + lc)*16 + (g ^ lc))*8;
      bfrag bh = *(const bfrag*)&Ws_hi[boff];
      bfrag bl = *(const bfrag*)&Ws_lo[boff];
      acc[ct] = __builtin_amdgcn_mfma_f32_16x16x32_bf16(ah, bh, acc[ct], 0, 0, 0);
      acc[ct] = __builtin_amdgcn_mfma_f32_16x16x32_bf16(ah, bl, acc[ct], 0, 0, 0);
      acc[ct] = __builtin_amdgcn_mfma_f32_16x16x32_bf16(al, bh, acc[ct], 0, 0, 0);
    }
  }

  // epilogue: C/D map col=lane&15, row=(lane>>4)*4+r
  int mbase = rowblk*64 + wave*16 + kg*4;
  #pragma unroll
  for (int r = 0; r < 4; r++){
    int m = mbase + r;
    bool ok = (m < N);
    float pi = 0.f, pj = 0.f;
    #pragma unroll
    for (int ct = 0; ct < 4; ct++){
      float v = acc[ct][r];
      if (ok) X[(size_t)m*EMBD + head*64 + ct*16 + lc] = v;
      pi += v*atti_l[ct]; pj += v*attj_l[ct];
    }
    pi += __shfl_xor(pi, 1); pi += __shfl_xor(pi, 2);
    pi += __shfl_xor(pi, 4); pi += __shfl_xor(pi, 8);
    pj += __shfl_xor(pj, 1); pj += __shfl_xor(pj, 2);
    pj += __shfl_xor(pj, 4); pj += __shfl_xor(pj, 8);
    if (ok && lc == 0){ ai4[(size_t)m*4 + head] = pi; aj4[(size_t)m*4 + head] = pj; }
  }
}

// Count pass: slot trick — atomicAdd's RETURN VALUE is this edge's slot.
__global__ void k_count(const int* __restrict__ ei, const int* __restrict__ msk,
    int* __restrict__ count2, int* __restrict__ slot_src, int* __restrict__ slot_dst,
    int E, int N){
  int e = blockIdx.x*256 + threadIdx.x;
  if (e >= E) return;
  int s = ei[e], d = ei[E + e];
  slot_src[e] = atomicAdd(&count2[s], 1);
  slot_dst[e] = msk[e] ? atomicAdd(&count2[N + d], 1) : -1;
}

// exclusive scan over count2 (length M=2N) -> offs2 (3 kernels)
__global__ void k_scan1(const int* __restrict__ count, int* __restrict__ offs,
                        int* __restrict__ bsum, int M){
  __shared__ int sm[256];
  int t = threadIdx.x, i = blockIdx.x*256 + t;
  int v = (i < M) ? count[i] : 0;
  sm[t] = v; __syncthreads();
  for (int o = 1; o < 256; o <<= 1){
    int u = (t >= o) ? sm[t-o] : 0;
    __syncthreads();
    sm[t] += u;
    __syncthreads();
  }
  if (i < M) offs[i] = sm[t] - v;
  if (t == 255) bsum[blockIdx.x] = sm[255];
}

__global__ void k_scan2(int* __restrict__ bsum, int NB){
  __shared__ int sm[1024];
  int t = threadIdx.x;
  int v = (t < NB) ? bsum[t] : 0;
  sm[t] = v; __syncthreads();
  for (int o = 1; o < 1024; o <<= 1){
    int u = (t >= o) ? sm[t-o] : 0;
    __syncthreads();
    sm[t] += u;
    __syncthreads();
  }
  if (t < NB) bsum[t] = sm[t] - v;   // exclusive
}

__global__ void k_scan3(int* __restrict__ offs, const int* __restrict__ bsum, int M){
  int i = blockIdx.x*256 + threadIdx.x;
  if (i < M) offs[i] += bsum[blockIdx.x];
}

// Atomic-free fill: src-list stores DST node id; dst-list stores SRC id.
__global__ void k_fill(const int* __restrict__ ei, const int* __restrict__ slot_src,
    const int* __restrict__ slot_dst, const int* __restrict__ offs2,
    int* __restrict__ elist_src, int* __restrict__ elist_dst, int E, int N){
  int e = blockIdx.x*256 + threadIdx.x;
  if (e >= E) return;
  int s = ei[e], d = ei[E + e];
  elist_src[offs2[s] + slot_src[e]] = d;
  int sd = slot_dst[e];
  if (sd >= 0) elist_dst[offs2[N + d] + sd] = s;
}

// Softmax denominators via gather-reduction over the src-list (NO atomics).
// Stores RECIPROCALS. exp without max-shift: |logit| <= ~8 here, identical math.
__global__ __launch_bounds__(256) void k_denom(const int* __restrict__ count2,
    const int* __restrict__ offs2, const int* __restrict__ elist_src,
    const float4* __restrict__ ai4, const float4* __restrict__ aj4,
    float4* __restrict__ denom4, int N){
  int g = threadIdx.x >> 4, l = threadIdx.x & 15;
  int n = blockIdx.x*16 + g;
  if (n >= N) return;
  int deg = count2[n];
  if (deg == 0) return;                 // never read downstream
  int base = offs2[n];
  float4 xj = aj4[n];                   // uniform in group -> broadcast
  float s0 = 0.f, s1 = 0.f, s2 = 0.f;
  for (int j = l; j < deg; j += 16){
    int d = elist_src[base + j];
    float4 xi = ai4[d];
    float a0 = xi.x + xj.x; a0 = a0 >= 0.f ? a0 : 0.2f*a0; s0 += expf(a0);
    float a1 = xi.y + xj.y; a1 = a1 >= 0.f ? a1 : 0.2f*a1; s1 += expf(a1);
    float a2 = xi.z + xj.z; a2 = a2 >= 0.f ? a2 : 0.2f*a2; s2 += expf(a2);
  }
  s0 += __shfl_xor(s0, 1); s0 += __shfl_xor(s0, 2); s0 += __shfl_xor(s0, 4); s0 += __shfl_xor(s0, 8);
  s1 += __shfl_xor(s1, 1); s1 += __shfl_xor(s1, 2); s1 += __shfl_xor(s1, 4); s1 += __shfl_xor(s1, 8);
  s2 += __shfl_xor(s2, 1); s2 += __shfl_xor(s2, 2); s2 += __shfl_xor(s2, 4); s2 += __shfl_xor(s2, 8);
  if (l == 0)
    denom4[n] = make_float4(1.f/(s0 + 1e-16f), 1.f/(s1 + 1e-16f), 1.f/(s2 + 1e-16f), 0.f);
}

// Gather-aggregate per dst node (wave per node) + bias + LeakyReLU(0.1).
__global__ __launch_bounds__(256) void k_aggr(const float* __restrict__ X,
    const int* __restrict__ count2, const int* __restrict__ offs2,
    const int* __restrict__ elist_dst, const float4* __restrict__ ai4,
    const float4* __restrict__ aj4, const float4* __restrict__ denom4,
    const float* __restrict__ bias, float* __restrict__ hact, int N){
  int w = threadIdx.x >> 6, l = threadIdx.x & 63;
  int n = blockIdx.x*4 + w;
  if (n >= N) return;
  int deg = count2[N + n], base = offs2[N + n];
  float4 xi = ai4[n];
  float ac0 = 0.f, ac1 = 0.f, ac2 = 0.f;
  #pragma unroll 4
  for (int j = 0; j < deg; j++){
    int s = elist_dst[base + j];
    float4 xj = aj4[s];
    float4 rn = denom4[s];
    float a0 = xi.x + xj.x; a0 = a0 >= 0.f ? a0 : 0.2f*a0; float c0 = expf(a0)*rn.x;
    float a1 = xi.y + xj.y; a1 = a1 >= 0.f ? a1 : 0.2f*a1; float c1 = expf(a1)*rn.y;
    float a2 = xi.z + xj.z; a2 = a2 >= 0.f ? a2 : 0.2f*a2; float c2 = expf(a2)*rn.z;
    const float* xr = X + (size_t)s*EMBD;
    ac0 += c0 * xr[l];
    ac1 += c1 * xr[64 + l];
    ac2 += c2 * xr[128 + l];
  }
  float* o = hact + (size_t)n*EMBD;
  float v0 = ac0 + bias[l];       v0 = v0 >= 0.f ? v0 : 0.1f*v0; o[l]       = v0;
  float v1 = ac1 + bias[64 + l];  v1 = v1 >= 0.f ? v1 : 0.1f*v1; o[64 + l]  = v1;
  float v2 = ac2 + bias[128 + l]; v2 = v2 >= 0.f ? v2 : 0.1f*v2; o[128 + l] = v2;
}

// BN stats stage 1: SB blocks x 192 threads, float4 loads, LDS tree.
__global__ __launch_bounds__(192) void k_stat1(const float4* __restrict__ h4,
    float4* __restrict__ part4, int N){
  int t = threadIdx.x;
  int fcol = t % 48, rg = t / 48;       // rg in 0..3
  float4 s = make_float4(0.f,0.f,0.f,0.f);
  float4 q = make_float4(0.f,0.f,0.f,0.f);
  for (int r = blockIdx.x*4 + rg; r < N; r += SB*4){
    float4 v = h4[(size_t)r*48 + fcol];
    s.x += v.x; s.y += v.y; s.z += v.z; s.w += v.w;
    q.x += v.x*v.x; q.y += v.y*v.y; q.z += v.z*v.z; q.w += v.w*v.w;
  }
  __shared__ float4 sms[192], smq[192];
  sms[t] = s; smq[t] = q;
  __syncthreads();
  if (rg < 2){ f4add(sms[t], sms[t+96]); f4add(smq[t], smq[t+96]); }
  __syncthreads();
  if (rg == 0){
    f4add(sms[t], sms[t+48]); f4add(smq[t], smq[t+48]);
    part4[(size_t)blockIdx.x*96 + fcol]      = sms[t];
    part4[(size_t)blockIdx.x*96 + 48 + fcol] = smq[t];
  }
}

// BN stats stage 2: 48 blocks (one float4-channel each) x 256 threads.
__global__ __launch_bounds__(256) void k_stat2(const float4* __restrict__ part4,
    float4* __restrict__ stats4, int N){
  int j = blockIdx.x, t = threadIdx.x;
  float4 s = make_float4(0.f,0.f,0.f,0.f);
  float4 q = make_float4(0.f,0.f,0.f,0.f);
  for (int b = t; b < SB; b += 256){
    f4add(s, part4[(size_t)b*96 + j]);
    f4add(q, part4[(size_t)b*96 + 48 + j]);
  }
  #pragma unroll
  for (int o = 32; o > 0; o >>= 1){
    s.x += __shfl_xor(s.x,o); s.y += __shfl_xor(s.y,o);
    s.z += __shfl_xor(s.z,o); s.w += __shfl_xor(s.w,o);
    q.x += __shfl_xor(q.x,o); q.y += __shfl_xor(q.y,o);
    q.z += __shfl_xor(q.z,o); q.w += __shfl_xor(q.w,o);
  }
  __shared__ float4 ws[4], wq[4];
  int wv = t >> 6;
  if ((t & 63) == 0){ ws[wv] = s; wq[wv] = q; }
  __syncthreads();
  if (t == 0){
    f4add(ws[0], ws[1]); f4add(ws[0], ws[2]); f4add(ws[0], ws[3]);
    f4add(wq[0], wq[1]); f4add(wq[0], wq[2]); f4add(wq[0], wq[3]);
    float inv = 1.f / (float)N;
    float4 mean = make_float4(ws[0].x*inv, ws[0].y*inv, ws[0].z*inv, ws[0].w*inv);
    float4 rstd;
    rstd.x = rsqrtf(wq[0].x*inv - mean.x*mean.x + 1e-5f);
    rstd.y = rsqrtf(wq[0].y*inv - mean.y*mean.y + 1e-5f);
    rstd.z = rsqrtf(wq[0].z*inv - mean.z*mean.z + 1e-5f);
    rstd.w = rsqrtf(wq[0].w*inv - mean.w*mean.w + 1e-5f);
    stats4[j] = mean;
    stats4[48 + j] = rstd;
  }
}

// final: mean over 4 layers, then affine BN (commutes since per-channel affine)
__global__ void k_final(const float* __restrict__ hact, const float* __restrict__ stats,
    const float* __restrict__ gamma, const float* __restrict__ beta,
    const int* __restrict__ sgs, float* __restrict__ out, int total){
  int o = blockIdx.x*256 + threadIdx.x;
  if (o >= total) return;
  int S = *sgs;
  int c  = o % EMBD;
  int rs = o / EMBD;
  int b  = rs / S;
  int s  = rs % S;
  size_t n0 = (size_t)b*4*S + s;
  float v = 0.25f * (hact[(n0      )*EMBD + c] + hact[(n0 +   S)*EMBD + c] +
                     hact[(n0 + 2*S)*EMBD + c] + hact[(n0 + 3*S)*EMBD + c]);
  out[o] = gamma[c] * ((v - stats[c]) * stats[192 + c]) + beta[c];
}

extern "C" void kernel_launch(void* const* d_in, const int* in_sizes, int n_in,
                              void* d_out, int out_size, void* d_ws, size_t ws_size,
                              hipStream_t stream){
  const float* subx  = (const float*)d_in[0];
  const int*   ei    = (const int*)d_in[1];
  const int*   msk   = (const int*)d_in[2];
  const float* W     = (const float*)d_in[3];
  const float* att   = (const float*)d_in[4];
  const float* bias  = (const float*)d_in[5];
  const float* gamma = (const float*)d_in[6];
  const float* beta  = (const float*)d_in[7];
  const int*   sgs   = (const int*)d_in[9];
  float* out = (float*)d_out;

  int N = in_sizes[0] / DIN;     // 64000
  int E = in_sizes[1] / 2;       // 512000

  // workspace layout (all chunks 16B aligned)
  float*  X         = (float*)d_ws;                    // N*192
  float*  hact      = X + (size_t)N*EMBD;              // N*192
  float*  denom4    = hact + (size_t)N*EMBD;           // N*4 (reciprocals)
  float*  ai4       = denom4 + (size_t)N*4;            // N*4
  float*  aj4       = ai4 + (size_t)N*4;               // N*4
  int*    count2    = (int*)(aj4 + (size_t)N*4);       // 2N  (zeroed in k_gemm)
  int*    offs2     = count2 + 2*(size_t)N;            // 2N
  int*    slot_src  = offs2 + 2*(size_t)N;             // E
  int*    slot_dst  = slot_src + E;                    // E
  int*    elist_src = slot_dst + E;                    // E
  int*    elist_dst = elist_src + E;                   // E
  int*    bsum      = elist_dst + E;                   // 1024
  float*  part      = (float*)(bsum + 1024);           // SB*96*4 floats
  float*  stats     = part + (size_t)SB*96*4;          // 384

  int EB  = (E + 255)/256;       // edge blocks
  int MB2 = (N + 63)/64;         // 64-row blocks (gemm)
  int G   = MB2*3;               // gemm grid (3000: %8==0 -> XCD swizzle on)
  int M2  = 2*N;                 // scan length
  int NB2 = (M2 + 255)/256;      // scan blocks

  k_gemm <<<G, 256, 0, stream>>>(subx, W, att, X, ai4, aj4,
                                 (unsigned*)count2, (long)M2, N, G);
  k_count<<<EB, 256, 0, stream>>>(ei, msk, count2, slot_src, slot_dst, E, N);
  k_scan1<<<NB2, 256, 0, stream>>>(count2, offs2, bsum, M2);
  k_scan2<<<1, 1024, 0, stream>>>(bsum, NB2);
  k_scan3<<<NB2, 256, 0, stream>>>(offs2, bsum, M2);
  k_fill <<<EB, 256, 0, stream>>>(ei, slot_src, slot_dst, offs2, elist_src, elist_dst, E, N);
  k_denom<<<(N + 15)/16, 256, 0, stream>>>(count2, offs2, elist_src,
                                           (const float4*)ai4, (const float4*)aj4,
                                           (float4*)denom4, N);
  k_aggr <<<(N + 3)/4, 256, 0, stream>>>(X, count2, offs2, elist_dst,
                                         (const float4*)ai4, (const float4*)aj4,
                                         (const float4*)denom4, bias, hact, N);
  k_stat1<<<SB, 192, 0, stream>>>((const float4*)hact, (float4*)part, N);
  k_stat2<<<48, 256, 0, stream>>>((const float4*)part, (float4*)stats, N);
  k_final<<<(out_size + 255)/256, 256, 0, stream>>>(hact, stats, gamma, beta, sgs, out, out_size);
}

// Round 10
// 254.804 us; speedup vs baseline: 1.9625x; 1.0410x over previous
//
#include <hip/hip_runtime.h>

#define EMBD 192
#define DIN 128
#define SB 1024   // stat stage-1 blocks

typedef __bf16 bfrag __attribute__((ext_vector_type(8)));
typedef float  f32x4 __attribute__((ext_vector_type(4)));

__device__ __forceinline__ void f4add(float4& a, const float4& b){
  a.x += b.x; a.y += b.y; a.z += b.z; a.w += b.w;
}
// round-to-nearest-even f32 -> bf16 (bit trick)
__device__ __forceinline__ unsigned short f2bf(float f){
  unsigned u = __float_as_uint(f);
  unsigned r = u + 0x7fffu + ((u >> 16) & 1u);
  return (unsigned short)(r >> 16);
}
__device__ __forceinline__ float bf2f(unsigned short h){
  return __uint_as_float(((unsigned)h) << 16);
}

// X[N,192] = A[N,128] @ W[192,128]^T via split-bf16 MFMA (3-term: hh+hl+lh,
// error ~2^-17). Block = 64 rows x 64 cols (one head); 4 waves.
__global__ __launch_bounds__(256) void k_gemm(const float* __restrict__ A,
      const float* __restrict__ W, const float* __restrict__ att,
      float* __restrict__ X, float* __restrict__ ai4, float* __restrict__ aj4,
      unsigned* __restrict__ zbuf, long zcount, int N, int G){
  {
    long i = (long)blockIdx.x*blockDim.x + threadIdx.x;
    long st = (long)gridDim.x*blockDim.x;
    for (; i < zcount; i += st) zbuf[i] = 0u;
  }

  int flat = blockIdx.x;
  int L = (G % 8 == 0) ? ((flat & 7)*(G >> 3) + (flat >> 3)) : flat;
  int rowblk = L / 3, head = L - rowblk*3;

  __shared__ unsigned short As_hi[8192], As_lo[8192];   // [64 rows][128 k] bf16
  __shared__ unsigned short Ws_hi[8192], Ws_lo[8192];   // [64 cols][128 k] bf16
  int t = threadIdx.x;

  const float4* Ag = (const float4*)A;
  const float4* Wg = (const float4*)W + (size_t)(head*64)*32;
  #pragma unroll
  for (int i = 0; i < 8; i++){
    int idx = i*256 + t;
    int r = idx >> 5, c4 = idx & 31;
    int g = (c4 >> 1) ^ (r & 15);                 // swizzled 16B granule
    int base = (r*16 + g)*8 + (c4 & 1)*4;
    int row = rowblk*64 + r; if (row >= N) row = N - 1;
    float4 va = Ag[(size_t)row*32 + c4];
    float4 vw = Wg[(size_t)idx];
    unsigned short h; float lo;
    ushort4 ah, al, wh, wl;
    h = f2bf(va.x); lo = va.x - bf2f(h); ah.x = h; al.x = f2bf(lo);
    h = f2bf(va.y); lo = va.y - bf2f(h); ah.y = h; al.y = f2bf(lo);
    h = f2bf(va.z); lo = va.z - bf2f(h); ah.z = h; al.z = f2bf(lo);
    h = f2bf(va.w); lo = va.w - bf2f(h); ah.w = h; al.w = f2bf(lo);
    *(ushort4*)&As_hi[base] = ah; *(ushort4*)&As_lo[base] = al;
    h = f2bf(vw.x); lo = vw.x - bf2f(h); wh.x = h; wl.x = f2bf(lo);
    h = f2bf(vw.y); lo = vw.y - bf2f(h); wh.y = h; wl.y = f2bf(lo);
    h = f2bf(vw.z); lo = vw.z - bf2f(h); wh.z = h; wl.z = f2bf(lo);
    h = f2bf(vw.w); lo = vw.w - bf2f(h); wh.w = h; wl.w = f2bf(lo);
    *(ushort4*)&Ws_hi[base] = wh; *(ushort4*)&Ws_lo[base] = wl;
  }

  int wave = t >> 6, lane = t & 63;
  int lc = lane & 15, kg = lane >> 4;
  float atti_l[4], attj_l[4];
  #pragma unroll
  for (int ct = 0; ct < 4; ct++){
    atti_l[ct] = att[head*128 + ct*16 + lc];
    attj_l[ct] = att[head*128 + 64 + ct*16 + lc];
  }
  __syncthreads();

  int arow = wave*16 + lc;
  f32x4 acc[4];
  #pragma unroll
  for (int ct = 0; ct < 4; ct++) acc[ct] = (f32x4){0.f, 0.f, 0.f, 0.f};

  #pragma unroll
  for (int ks = 0; ks < 4; ks++){
    int g = ks*4 + kg;
    int aoff = (arow*16 + (g ^ (arow & 15)))*8;
    bfrag ah = *(const bfrag*)&As_hi[aoff];
    bfrag al = *(const bfrag*)&As_lo[aoff];
    #pragma unroll
    for (int ct = 0; ct < 4; ct++){
      int boff = ((ct*16 + lc)*16 + (g ^ lc))*8;
      bfrag bh = *(const bfrag*)&Ws_hi[boff];
      bfrag bl = *(const bfrag*)&Ws_lo[boff];
      acc[ct] = __builtin_amdgcn_mfma_f32_16x16x32_bf16(ah, bh, acc[ct], 0, 0, 0);
      acc[ct] = __builtin_amdgcn_mfma_f32_16x16x32_bf16(ah, bl, acc[ct], 0, 0, 0);
      acc[ct] = __builtin_amdgcn_mfma_f32_16x16x32_bf16(al, bh, acc[ct], 0, 0, 0);
    }
  }

  int mbase = rowblk*64 + wave*16 + kg*4;
  #pragma unroll
  for (int r = 0; r < 4; r++){
    int m = mbase + r;
    bool ok = (m < N);
    float pi = 0.f, pj = 0.f;
    #pragma unroll
    for (int ct = 0; ct < 4; ct++){
      float v = acc[ct][r];
      if (ok) X[(size_t)m*EMBD + head*64 + ct*16 + lc] = v;
      pi += v*atti_l[ct]; pj += v*attj_l[ct];
    }
    pi += __shfl_xor(pi, 1); pi += __shfl_xor(pi, 2);
    pi += __shfl_xor(pi, 4); pi += __shfl_xor(pi, 8);
    pj += __shfl_xor(pj, 1); pj += __shfl_xor(pj, 2);
    pj += __shfl_xor(pj, 4); pj += __shfl_xor(pj, 8);
    if (ok && lc == 0){ ai4[(size_t)m*4 + head] = pi; aj4[(size_t)m*4 + head] = pj; }
  }
}

// Count pass: slot trick — atomicAdd's RETURN VALUE is this edge's slot.
__global__ void k_count(const int* __restrict__ ei, const int* __restrict__ msk,
    int* __restrict__ count2, int* __restrict__ slot_src, int* __restrict__ slot_dst,
    int E, int N){
  int e = blockIdx.x*256 + threadIdx.x;
  if (e >= E) return;
  int s = ei[e], d = ei[E + e];
  slot_src[e] = atomicAdd(&count2[s], 1);
  slot_dst[e] = msk[e] ? atomicAdd(&count2[N + d], 1) : -1;
}

// exclusive scan over count2 (length M=2N) -> offs2 (3 kernels)
__global__ void k_scan1(const int* __restrict__ count, int* __restrict__ offs,
                        int* __restrict__ bsum, int M){
  __shared__ int sm[256];
  int t = threadIdx.x, i = blockIdx.x*256 + t;
  int v = (i < M) ? count[i] : 0;
  sm[t] = v; __syncthreads();
  for (int o = 1; o < 256; o <<= 1){
    int u = (t >= o) ? sm[t-o] : 0;
    __syncthreads();
    sm[t] += u;
    __syncthreads();
  }
  if (i < M) offs[i] = sm[t] - v;
  if (t == 255) bsum[blockIdx.x] = sm[255];
}

__global__ void k_scan2(int* __restrict__ bsum, int* __restrict__ gtot, int NB){
  __shared__ int sm[1024];
  int t = threadIdx.x;
  int v = (t < NB) ? bsum[t] : 0;
  sm[t] = v; __syncthreads();
  for (int o = 1; o < 1024; o <<= 1){
    int u = (t >= o) ? sm[t-o] : 0;
    __syncthreads();
    sm[t] += u;
    __syncthreads();
  }
  if (t < NB) bsum[t] = sm[t] - v;   // exclusive
  if (t == NB-1) *gtot = sm[t];      // grand total (= E + masked_total)
}

__global__ void k_scan3(int* __restrict__ offs, const int* __restrict__ bsum, int M){
  int i = blockIdx.x*256 + threadIdx.x;
  if (i < M) offs[i] += bsum[blockIdx.x];
}

// Atomic-free fill: src-list stores DST node id; masked dst-list stores {s,d}
// pairs at RELATIVE slot (offs2[N+d]-E).
__global__ void k_fill(const int* __restrict__ ei, const int* __restrict__ slot_src,
    const int* __restrict__ slot_dst, const int* __restrict__ offs2,
    int* __restrict__ elist_src, int2* __restrict__ pairs_dst, int E, int N){
  int e = blockIdx.x*256 + threadIdx.x;
  if (e >= E) return;
  int s = ei[e], d = ei[E + e];
  elist_src[offs2[s] + slot_src[e]] = d;
  int sd = slot_dst[e];
  if (sd >= 0) pairs_dst[offs2[N + d] + sd - E] = make_int2(s, d);
}

// Softmax denominators via gather-reduction over the src-list (NO atomics).
// Stores RECIPROCALS. __expf (v_exp_f32 fast path).
__global__ __launch_bounds__(256) void k_denom(const int* __restrict__ count2,
    const int* __restrict__ offs2, const int* __restrict__ elist_src,
    const float4* __restrict__ ai4, const float4* __restrict__ aj4,
    float4* __restrict__ denom4, int N){
  int g = threadIdx.x >> 4, l = threadIdx.x & 15;
  int n = blockIdx.x*16 + g;
  if (n >= N) return;
  int deg = count2[n];
  if (deg == 0) return;                 // never read downstream
  int base = offs2[n];
  float4 xj = aj4[n];                   // uniform in group -> broadcast
  float s0 = 0.f, s1 = 0.f, s2 = 0.f;
  for (int j = l; j < deg; j += 16){
    int d = elist_src[base + j];
    float4 xi = ai4[d];
    float a0 = xi.x + xj.x; a0 = a0 >= 0.f ? a0 : 0.2f*a0; s0 += __expf(a0);
    float a1 = xi.y + xj.y; a1 = a1 >= 0.f ? a1 : 0.2f*a1; s1 += __expf(a1);
    float a2 = xi.z + xj.z; a2 = a2 >= 0.f ? a2 : 0.2f*a2; s2 += __expf(a2);
  }
  s0 += __shfl_xor(s0, 1); s0 += __shfl_xor(s0, 2); s0 += __shfl_xor(s0, 4); s0 += __shfl_xor(s0, 8);
  s1 += __shfl_xor(s1, 1); s1 += __shfl_xor(s1, 2); s1 += __shfl_xor(s1, 4); s1 += __shfl_xor(s1, 8);
  s2 += __shfl_xor(s2, 1); s2 += __shfl_xor(s2, 2); s2 += __shfl_xor(s2, 4); s2 += __shfl_xor(s2, 8);
  if (l == 0)
    denom4[n] = make_float4(1.f/(s0 + 1e-16f), 1.f/(s1 + 1e-16f), 1.f/(s2 + 1e-16f), 0.f);
}

// Slot-parallel coefficient finalize: one thread per masked CSR slot.
__global__ void k_coef(const int2* __restrict__ pairs, const float4* __restrict__ ai4,
    const float4* __restrict__ aj4, const float4* __restrict__ denom4,
    const int* __restrict__ gtot, float4* __restrict__ ecoef, int E){
  int i = blockIdx.x*256 + threadIdx.x;
  int total = *gtot - E;               // masked slot count
  if (i >= total) return;
  int2 p = pairs[i];                   // {s, d}
  float4 xj = aj4[p.x];
  float4 xi = ai4[p.y];
  float4 rn = denom4[p.x];
  float a0 = xi.x + xj.x; a0 = a0 >= 0.f ? a0 : 0.2f*a0;
  float a1 = xi.y + xj.y; a1 = a1 >= 0.f ? a1 : 0.2f*a1;
  float a2 = xi.z + xj.z; a2 = a2 >= 0.f ? a2 : 0.2f*a2;
  ecoef[i] = make_float4(__int_as_float(p.x),
                         __expf(a0)*rn.x, __expf(a1)*rn.y, __expf(a2)*rn.z);
}

// Gather-aggregate per dst node (wave per node) + bias + LeakyReLU(0.1).
// Lane l<48 owns channels [4l,4l+4) -> full 768-B X row = ONE float4/lane.
__global__ __launch_bounds__(256) void k_aggr(const float4* __restrict__ X4,
    const int* __restrict__ count2, const int* __restrict__ offs2,
    const float4* __restrict__ ecoef, const float4* __restrict__ bias4,
    float4* __restrict__ hact4, int N, int E){
  int w = threadIdx.x >> 6, l = threadIdx.x & 63;
  int n = blockIdx.x*4 + w;
  if (n >= N) return;
  int deg = count2[N + n], base = offs2[N + n] - E;
  int lc = l < 48 ? l : 47;
  int hsel = lc >> 4;                  // 0..2
  float4 ac = make_float4(0.f,0.f,0.f,0.f);
  #pragma unroll 4
  for (int j = 0; j < deg; j++){
    float4 q = ecoef[base + j];        // wave-uniform broadcast
    int s = __float_as_int(q.x);
    float c = hsel == 0 ? q.y : (hsel == 1 ? q.z : q.w);
    float4 v = X4[(size_t)s*48 + lc];
    ac.x += c*v.x; ac.y += c*v.y; ac.z += c*v.z; ac.w += c*v.w;
  }
  if (l < 48){
    float4 b = bias4[lc];
    float4 o;
    o.x = ac.x + b.x; o.x = o.x >= 0.f ? o.x : 0.1f*o.x;
    o.y = ac.y + b.y; o.y = o.y >= 0.f ? o.y : 0.1f*o.y;
    o.z = ac.z + b.z; o.z = o.z >= 0.f ? o.z : 0.1f*o.z;
    o.w = ac.w + b.w; o.w = o.w >= 0.f ? o.w : 0.1f*o.w;
    hact4[(size_t)n*48 + lc] = o;
  }
}

// BN stats stage 1: SB blocks x 192 threads, float4 loads, LDS tree.
__global__ __launch_bounds__(192) void k_stat1(const float4* __restrict__ h4,
    float4* __restrict__ part4, int N){
  int t = threadIdx.x;
  int fcol = t % 48, rg = t / 48;       // rg in 0..3
  float4 s = make_float4(0.f,0.f,0.f,0.f);
  float4 q = make_float4(0.f,0.f,0.f,0.f);
  for (int r = blockIdx.x*4 + rg; r < N; r += SB*4){
    float4 v = h4[(size_t)r*48 + fcol];
    s.x += v.x; s.y += v.y; s.z += v.z; s.w += v.w;
    q.x += v.x*v.x; q.y += v.y*v.y; q.z += v.z*v.z; q.w += v.w*v.w;
  }
  __shared__ float4 sms[192], smq[192];
  sms[t] = s; smq[t] = q;
  __syncthreads();
  if (rg < 2){ f4add(sms[t], sms[t+96]); f4add(smq[t], smq[t+96]); }
  __syncthreads();
  if (rg == 0){
    f4add(sms[t], sms[t+48]); f4add(smq[t], smq[t+48]);
    part4[(size_t)blockIdx.x*96 + fcol]      = sms[t];
    part4[(size_t)blockIdx.x*96 + 48 + fcol] = smq[t];
  }
}

// BN stats stage 2: 48 blocks (one float4-channel each) x 256 threads.
__global__ __launch_bounds__(256) void k_stat2(const float4* __restrict__ part4,
    float4* __restrict__ stats4, int N){
  int j = blockIdx.x, t = threadIdx.x;
  float4 s = make_float4(0.f,0.f,0.f,0.f);
  float4 q = make_float4(0.f,0.f,0.f,0.f);
  for (int b = t; b < SB; b += 256){
    f4add(s, part4[(size_t)b*96 + j]);
    f4add(q, part4[(size_t)b*96 + 48 + j]);
  }
  #pragma unroll
  for (int o = 32; o > 0; o >>= 1){
    s.x += __shfl_xor(s.x,o); s.y += __shfl_xor(s.y,o);
    s.z += __shfl_xor(s.z,o); s.w += __shfl_xor(s.w,o);
    q.x += __shfl_xor(q.x,o); q.y += __shfl_xor(q.y,o);
    q.z += __shfl_xor(q.z,o); q.w += __shfl_xor(q.w,o);
  }
  __shared__ float4 ws[4], wq[4];
  int wv = t >> 6;
  if ((t & 63) == 0){ ws[wv] = s; wq[wv] = q; }
  __syncthreads();
  if (t == 0){
    f4add(ws[0], ws[1]); f4add(ws[0], ws[2]); f4add(ws[0], ws[3]);
    f4add(wq[0], wq[1]); f4add(wq[0], wq[2]); f4add(wq[0], wq[3]);
    float inv = 1.f / (float)N;
    float4 mean = make_float4(ws[0].x*inv, ws[0].y*inv, ws[0].z*inv, ws[0].w*inv);
    float4 rstd;
    rstd.x = rsqrtf(wq[0].x*inv - mean.x*mean.x + 1e-5f);
    rstd.y = rsqrtf(wq[0].y*inv - mean.y*mean.y + 1e-5f);
    rstd.z = rsqrtf(wq[0].z*inv - mean.z*mean.z + 1e-5f);
    rstd.w = rsqrtf(wq[0].w*inv - mean.w*mean.w + 1e-5f);
    stats4[j] = mean;
    stats4[48 + j] = rstd;
  }
}

// final: mean over 4 layers, then affine BN (commutes since per-channel affine)
__global__ void k_final(const float* __restrict__ hact, const float* __restrict__ stats,
    const float* __restrict__ gamma, const float* __restrict__ beta,
    const int* __restrict__ sgs, float* __restrict__ out, int total){
  int o = blockIdx.x*256 + threadIdx.x;
  if (o >= total) return;
  int S = *sgs;
  int c  = o % EMBD;
  int rs = o / EMBD;
  int b  = rs / S;
  int s  = rs % S;
  size_t n0 = (size_t)b*4*S + s;
  float v = 0.25f * (hact[(n0      )*EMBD + c] + hact[(n0 +   S)*EMBD + c] +
                     hact[(n0 + 2*S)*EMBD + c] + hact[(n0 + 3*S)*EMBD + c]);
  out[o] = gamma[c] * ((v - stats[c]) * stats[192 + c]) + beta[c];
}

extern "C" void kernel_launch(void* const* d_in, const int* in_sizes, int n_in,
                              void* d_out, int out_size, void* d_ws, size_t ws_size,
                              hipStream_t stream){
  const float* subx  = (const float*)d_in[0];
  const int*   ei    = (const int*)d_in[1];
  const int*   msk   = (const int*)d_in[2];
  const float* W     = (const float*)d_in[3];
  const float* att   = (const float*)d_in[4];
  const float* bias  = (const float*)d_in[5];
  const float* gamma = (const float*)d_in[6];
  const float* beta  = (const float*)d_in[7];
  const int*   sgs   = (const int*)d_in[9];
  float* out = (float*)d_out;

  int N = in_sizes[0] / DIN;     // 64000
  int E = in_sizes[1] / 2;       // 512000

  // workspace layout (all chunks 16B aligned)
  float*  X         = (float*)d_ws;                    // N*192
  float*  hact      = X + (size_t)N*EMBD;              // N*192
  float*  denom4    = hact + (size_t)N*EMBD;           // N*4 (reciprocals)
  float*  ai4       = denom4 + (size_t)N*4;            // N*4
  float*  aj4       = ai4 + (size_t)N*4;               // N*4
  int*    count2    = (int*)(aj4 + (size_t)N*4);       // 2N  (zeroed in k_gemm)
  int*    offs2     = count2 + 2*(size_t)N;            // 2N
  int*    slot_src  = offs2 + 2*(size_t)N;             // E
  int*    slot_dst  = slot_src + E;                    // E
  int*    elist_src = slot_dst + E;                    // E
  int2*   pairs_dst = (int2*)(elist_src + E);          // E int2
  float4* ecoef     = (float4*)(pairs_dst + E);        // E float4
  int*    bsum      = (int*)(ecoef + E);               // 1024
  int*    gtot      = bsum + 1024;                     // 4 (pad)
  float*  part      = (float*)(gtot + 4);              // SB*96*4 floats
  float*  stats     = part + (size_t)SB*96*4;          // 384

  int EB  = (E + 255)/256;       // edge blocks
  int MB2 = (N + 63)/64;         // 64-row blocks (gemm)
  int G   = MB2*3;               // gemm grid (3000: %8==0 -> XCD swizzle on)
  int M2  = 2*N;                 // scan length
  int NB2 = (M2 + 255)/256;      // scan blocks

  k_gemm <<<G, 256, 0, stream>>>(subx, W, att, X, ai4, aj4,
                                 (unsigned*)count2, (long)M2, N, G);
  k_count<<<EB, 256, 0, stream>>>(ei, msk, count2, slot_src, slot_dst, E, N);
  k_scan1<<<NB2, 256, 0, stream>>>(count2, offs2, bsum, M2);
  k_scan2<<<1, 1024, 0, stream>>>(bsum, gtot, NB2);
  k_scan3<<<NB2, 256, 0, stream>>>(offs2, bsum, M2);
  k_fill <<<EB, 256, 0, stream>>>(ei, slot_src, slot_dst, offs2, elist_src, pairs_dst, E, N);
  k_denom<<<(N + 15)/16, 256, 0, stream>>>(count2, offs2, elist_src,
                                           (const float4*)ai4, (const float4*)aj4,
                                           (float4*)denom4, N);
  k_coef <<<EB, 256, 0, stream>>>(pairs_dst, (const float4*)ai4, (const float4*)aj4,
                                  (const float4*)denom4, gtot, ecoef, E);
  k_aggr <<<(N + 3)/4, 256, 0, stream>>>((const float4*)X, count2, offs2, ecoef,
                                         (const float4*)bias, (float4*)hact, N, E);
  k_stat1<<<SB, 192, 0, stream>>>((const float4*)hact, (float4*)part, N);
  k_stat2<<<48, 256, 0, stream>>>((const float4*)part, (float4*)stats, N);
  k_final<<<(out_size + 255)/256, 256, 0, stream>>>(hact, stats, gamma, beta, sgs, out, out_size);
}